// Round 3
// baseline (1112.393 us; speedup 1.0000x reference)
//
#include <hip/hip_runtime.h>
#include <hip/hip_bf16.h>

// CapsModel: B=64 N=32 H=W=16 A=16 K=3 stride=2 -> Ho=Wo=7, M=32, SD=4, D=16
// R19: conv routing = MFMA (R18 math, verified) restructured for latency:
//   ONE SITE PER WAVE, ZERO BARRIERS. Block = 4 waves = 4 independent sites
//   (grid 784). Each wave stages its own s_inp slice, runs all 72 quads,
//   reduces nkl purely in-wave (xor16/32), does LN in-wave, writes its own
//   s_v2 slice (same-wave LDS RAW, lgkmcnt-ordered). R18's cross-wave
//   s_part + 128-thread combine + 6 barriers/pass are gone.
//   LDS 45KB -> 3 blocks/CU -> 3 waves/SIMD resident independent streams
//   (R18: 2/SIMD + lockstep barriers => 7.5x stall factor, 306us).
//   launch_bounds (256,3): VGPR cap 170 (R18 used 116). Spill tell:
//   WRITE_SIZE must stay 6.27MB (= vout only).
// fc routing R16: 4 launches, prev-partial double-buffered. Unchanged.

#define LN_EPS 1e-5f

typedef _Float16 h2 __attribute__((ext_vector_type(2)));
typedef _Float16 half8_t __attribute__((ext_vector_type(8)));
typedef float float4_t __attribute__((ext_vector_type(4)));

__device__ __forceinline__ unsigned packh2(float a, float b) {
    const unsigned short ua = __builtin_bit_cast(unsigned short, (_Float16)a);
    const unsigned short ub = __builtin_bit_cast(unsigned short, (_Float16)b);
    return (unsigned)ua | ((unsigned)ub << 16);
}

// ---------------- weight transposes ----------------
// wTh [288][32][16] f16: row r = n*9+kl; inner idx = d*4+x (x-pairs adjacent).
__global__ __launch_bounds__(256) void transpose_wconv(
    const float* __restrict__ wconv, unsigned short* __restrict__ wTh)
{
    const int i = blockIdx.x * 256 + threadIdx.x;
    if (i < 147456) {
        const int x = i & 3, d = (i >> 2) & 3, mm = (i >> 4) & 31, r = i >> 9;
        const int n = r / 9, kl = r % 9;
        const float v = wconv[((kl * 32 + n) * 16 + x * 4 + d) * 32 + mm];
        wTh[i] = __builtin_bit_cast(unsigned short, (_Float16)v);
    }
}
// wT2b [1568][16][16] fp32: [n][m (pad 10->16, zeros)][x*4+d]
__global__ __launch_bounds__(256) void transpose_wfc(
    const float* __restrict__ wfc, float* __restrict__ wT2b)
{
    const int j = blockIdx.x * 256 + threadIdx.x;
    if (j < 401408) {
        const int xd = j & 15, mm = (j >> 4) & 15, n = j >> 8;
        const int x = xd >> 2, dd = xd & 3;
        wT2b[j] = (mm < 10) ? wfc[((n * 4 + x) * 4 + dd) * 10 + mm] : 0.f;
    }
}
// fused (roomy ws layout)
__global__ __launch_bounds__(256) void transpose_weights(
    const float* __restrict__ wconv, const float* __restrict__ wfc,
    unsigned short* __restrict__ wTh, float* __restrict__ wT2b)
{
    const int blk = blockIdx.x;
    if (blk < 576) {
        const int i = blk * 256 + threadIdx.x;
        if (i < 147456) {
            const int x = i & 3, d = (i >> 2) & 3, mm = (i >> 4) & 31, r = i >> 9;
            const int n = r / 9, kl = r % 9;
            const float v = wconv[((kl * 32 + n) * 16 + x * 4 + d) * 32 + mm];
            wTh[i] = __builtin_bit_cast(unsigned short, (_Float16)v);
        }
    } else {
        const int j = (blk - 576) * 256 + threadIdx.x;
        if (j < 401408) {
            const int xd = j & 15, mm = (j >> 4) & 15, n = j >> 8;
            const int x = xd >> 2, dd = xd & 3;
            wT2b[j] = (mm < 10) ? wfc[((n * 4 + x) * 4 + dd) * 10 + mm] : 0.f;
        }
    }
}

// ---------------- Stage 1: conv routing (MFMA, wave-per-site) ----------------
__global__ __launch_bounds__(256, 3) void conv_routing_kernel(
    const float* __restrict__ x,             // [64][32][16][16][16]
    const unsigned short* __restrict__ wTh,  // [288][32][16] f16, inner=d*4+x
    const float* __restrict__ ln1g,
    const float* __restrict__ ln1b,
    const int*   __restrict__ nroute,
    float* __restrict__ vout)                // [64][32][49][16]
{
    __shared__ unsigned short s_inp[4][288][16];  // 36,864 B (per-wave slices)
    __shared__ float s_v2[4][32][16];             //  8,192 B, v as [m][d*4+a]

    const int tid = threadIdx.x;
    const int wv  = tid >> 6;        // wave = site slot
    const int l   = tid & 63;
    const int hi  = l >> 4;          // K-chunk == C row-group == B nkl-offset
    const int c   = l & 15;          // C col = d*4+msub ; A row = (aj,aa)
    const int msub = c & 3;
    const int dq   = c >> 2;
    const int aj   = dq;             // A-row j  (same bits as dq)
    const int aa   = msub;           // A-row a  (same bits as msub)
    const bool partA = (aj == hi);   // block-diagonal participation

    const int site = blockIdx.x * 4 + wv;
    const int b = site / 49, hw = site % 49;
    const int h = hw / 7, w = hw % 7;

    // stage OWN site's inp (no barrier needed: wave-private slice)
    for (int it = 0; it < 18; ++it) {          // 288 rows * 4 quads / 64 lanes
        const int i = it * 64 + l;
        const int row = i >> 2, q = i & 3;
        const int n = row / 9, kl = row % 9;
        const int k = kl / 3, lw2 = kl % 3;
        const float4 val = *(const float4*)(
            x + ((((b * 32 + n) * 16 + (2 * h + k)) * 16 + (2 * w + lw2)) * 16 + q * 4));
        uint2 p;
        p.x = packh2(val.x, val.y);
        p.y = packh2(val.z, val.w);
        *(uint2*)(&s_inp[wv][row][q * 4]) = p;
    }

    const int R = *nroute;

    // per-lane invariant addresses
    // B (global): half-index = ((q*4+hi)*32 + m)*16 + d*4 ; m = 4t+msub
    const unsigned short* const bpl =
        wTh + (hi * 32 + msub) * 16 + dq * 4;
    // LN gains for this lane's (d=dq): i = a*4 + d
    const float g0 = ln1g[dq],      b0 = ln1b[dq];
    const float g1 = ln1g[4 + dq],  b1 = ln1b[4 + dq];
    const float g2 = ln1g[8 + dq],  b2 = ln1b[8 + dq];
    const float g3 = ln1g[12 + dq], b3 = ln1b[12 + dq];

    const float4_t z4 = {0.f, 0.f, 0.f, 0.f};

    for (int pass = 0; pass < R; ++pass) {
        float4_t vr[8];
        if (pass) {
#pragma unroll
            for (int t = 0; t < 8; ++t)
                vr[t] = *(const float4_t*)(&s_v2[wv][4 * t + msub][dq * 4]);
        }

        float4_t acc[8];
#pragma unroll
        for (int t = 0; t < 8; ++t) acc[t] = z4;

        // B double buffer; top half of each half8 stays zero (A off-diag too)
        uint4 Bbuf[2][8];
#pragma unroll
        for (int s = 0; s < 2; ++s)
#pragma unroll
            for (int t = 0; t < 8; ++t) {
                Bbuf[s][t].z = 0u; Bbuf[s][t].w = 0u;
            }
#pragma unroll
        for (int t = 0; t < 8; ++t) {          // preload quad 0
            const uint2 bv = *(const uint2*)(bpl + t * 64);
            Bbuf[0][t].x = bv.x; Bbuf[0][t].y = bv.y;
        }

#pragma unroll 2
        for (int q = 0; q < 72; ++q) {
            const int rowq = q * 4;
            // A fragment: row rowq+aj, elems aa*4.. ; off-diag lanes -> 0
            const uint2 av = *(const uint2*)(&s_inp[wv][rowq + aj][aa * 4]);
            uint4 au;
            au.x = partA ? av.x : 0u;
            au.y = partA ? av.y : 0u;
            au.z = 0u; au.w = 0u;
            const half8_t a8 = __builtin_bit_cast(half8_t, au);

            // prefetch next quad's B
            if (q < 71) {
                const unsigned short* bp2 = bpl + (q + 1) * 2048;
#pragma unroll
                for (int t = 0; t < 8; ++t) {
                    const uint2 bv = *(const uint2*)(bp2 + t * 64);
                    Bbuf[(q + 1) & 1][t].x = bv.x;
                    Bbuf[(q + 1) & 1][t].y = bv.y;
                }
            }

            if (pass == 0) {
#pragma unroll
                for (int t = 0; t < 8; ++t) {
                    const half8_t b8 = __builtin_bit_cast(half8_t, Bbuf[q & 1][t]);
                    acc[t] = __builtin_amdgcn_mfma_f32_16x16x32_f16(a8, b8, acc[t], 0, 0, 0);
                }
            } else {
                float4_t ct[8];
#pragma unroll
                for (int t = 0; t < 8; ++t) {
                    const half8_t b8 = __builtin_bit_cast(half8_t, Bbuf[q & 1][t]);
                    ct[t] = __builtin_amdgcn_mfma_f32_16x16x32_f16(a8, b8, z4, 0, 0, 0);
                }
                // logits: lg[nkl=rowq+hi][m=4t+msub] = sum_{a,d} vote * v
                float e[8];
#pragma unroll
                for (int t = 0; t < 8; ++t) {
                    float pt = ct[t][0] * vr[t][0];
                    pt = fmaf(ct[t][1], vr[t][1], pt);
                    pt = fmaf(ct[t][2], vr[t][2], pt);
                    pt = fmaf(ct[t][3], vr[t][3], pt);
                    pt += __shfl_xor(pt, 4, 64);   // sum over d
                    pt += __shfl_xor(pt, 8, 64);
                    e[t] = __expf(pt * 0.25f);
                }
                // softmax over m (8 in-lane tiles x 4 msub lanes)
                float zsum = ((e[0] + e[1]) + (e[2] + e[3]))
                           + ((e[4] + e[5]) + (e[6] + e[7]));
                zsum += __shfl_xor(zsum, 1, 64);
                zsum += __shfl_xor(zsum, 2, 64);
                const float rq = __builtin_amdgcn_rcpf(zsum * (1.f + 1e-10f));
#pragma unroll
                for (int t = 0; t < 8; ++t) {
                    const float qk = e[t] * rq;
                    acc[t] = acc[t] + ct[t] * qk;
                }
            }
        }

        // in-wave reduce over nkl-groups (hi): xor16, xor32 -> full 288 sum
#pragma unroll
        for (int t = 0; t < 8; ++t) {
#pragma unroll
            for (int r = 0; r < 4; ++r) {
                float v0 = acc[t][r];
                v0 += __shfl_xor(v0, 16, 64);
                v0 += __shfl_xor(v0, 32, 64);
                acc[t][r] = v0;
            }
        }
        const float scale = pass ? 1.f : (1.f / 32.f);
#pragma unroll
        for (int t = 0; t < 8; ++t) acc[t] = acc[t] * scale;

        // in-wave LN per m = 4t+msub: a in-lane, d over dq lane groups
#pragma unroll
        for (int t = 0; t < 8; ++t) {
            float s0 = (acc[t][0] + acc[t][1]) + (acc[t][2] + acc[t][3]);
            s0 += __shfl_xor(s0, 4, 64);
            s0 += __shfl_xor(s0, 8, 64);
            const float mu = s0 * (1.f / 16.f);
            float vvar = 0.f;
#pragma unroll
            for (int a = 0; a < 4; ++a) {
                const float d0 = acc[t][a] - mu;
                vvar = fmaf(d0, d0, vvar);
            }
            vvar += __shfl_xor(vvar, 4, 64);
            vvar += __shfl_xor(vvar, 8, 64);
            const float inv = rsqrtf(vvar * (1.f / 16.f) + LN_EPS);
            if (l < 16) {
                float4_t o;
                o[0] = (acc[t][0] - mu) * inv * g0 + b0;
                o[1] = (acc[t][1] - mu) * inv * g1 + b1;
                o[2] = (acc[t][2] - mu) * inv * g2 + b2;
                o[3] = (acc[t][3] - mu) * inv * g3 + b3;
                *(float4_t*)(&s_v2[wv][4 * t + msub][dq * 4]) = o;
            }
        }
        // same-wave LDS RAW (next pass's vr read); lgkmcnt-ordered, no barrier
    }

    // vout[m][i = a*4+d] from s_v2[m][d*4+a]
    for (int p = l; p < 512; p += 64) {
        const int mm = p >> 4, i = p & 15;
        vout[((b * 32 + mm) * 49 + hw) * 16 + i] = s_v2[wv][mm][(i & 3) * 4 + (i >> 2)];
    }
}

// ---------------- Stage 2: FC routing ----------------
// fc_pass: 512 blocks = 64 b x 8 chunks; 256 thr = 16 grp x 16 ml.
// For pass>=1, each block redundantly recomputes its b's u from the
// previous pass's partial (combine+LN in LDS) - no ubuf, no extra launch.
__global__ __launch_bounds__(256, 4) void fc_pass(
    const float* __restrict__ fcin,  // [64][1568][16]
    const float* __restrict__ wT2b,  // [1568][16][16] ([n][ml][x*4+d])
    const float* __restrict__ prev,  // [512][16][16] partial from pass-1 (or null)
    const float* __restrict__ ln2g,
    const float* __restrict__ ln2b,
    const int*   __restrict__ nroute,
    const int    pass,
    float* __restrict__ pout)        // [512][16][16]
{
    __shared__ float s_red[4][16][17];
    __shared__ float s_u[16][17];

    const int R = *nroute;
    if (pass >= R) return;
    const int blk = blockIdx.x;
    const int b = blk >> 3, c = blk & 7;
    const int tid = threadIdx.x;
    const int ml = tid & 15, grp = tid >> 4;
    const int wv = tid >> 6;

    float ur[16];
    if (pass) {
        // inline combine + LN: thread (mlf, ii)
        const int mlf = tid >> 4, ii = tid & 15;
        float s = 0.f;
#pragma unroll
        for (int c2 = 0; c2 < 8; ++c2)
            s += prev[((b * 8 + c2) * 16 + mlf) * 16 + ii];
        if (pass == 1) s *= 0.1f;   // pass-0 output carries the 1/Cls scale
        float mu = s;
#pragma unroll
        for (int off = 8; off >= 1; off >>= 1) mu += __shfl_xor(mu, off, 16);
        mu *= (1.f / 16.f);
        const float d0 = s - mu;
        float var = d0 * d0;
#pragma unroll
        for (int off = 8; off >= 1; off >>= 1) var += __shfl_xor(var, off, 16);
        var *= (1.f / 16.f);
        s_u[mlf][ii] = (s - mu) * rsqrtf(var + LN_EPS) * ln2g[ii] + ln2b[ii];
        __syncthreads();
#pragma unroll
        for (int i = 0; i < 16; ++i) ur[i] = s_u[ml][i];
    }

    const float* fb = fcin + (b * 1568 + c * 196) * 16;
    const float* wb = wT2b + (c * 196 * 16) * 16;

    float un[16];
#pragma unroll
    for (int i = 0; i < 16; ++i) un[i] = 0.f;

    for (int t = 0; t < 13; ++t) {
        const int off = t * 16 + grp;
        if (off >= 196) break;
        float iv[16], wv_[16];
        const float* ip = fb + off * 16;
        const float* wp = wb + (off * 16 + ml) * 16;
#pragma unroll
        for (int q = 0; q < 4; ++q) {
            *(float4*)(&iv[q * 4]) = *(const float4*)(ip + q * 4);
            *(float4*)(&wv_[q * 4]) = *(const float4*)(wp + q * 4);
        }
        float vote[16];
#pragma unroll
        for (int a = 0; a < 4; ++a) {
#pragma unroll
            for (int d = 0; d < 4; ++d) {
                float acc = iv[a * 4 + 0] * wv_[0 + d];
                acc = fmaf(iv[a * 4 + 1], wv_[4 + d], acc);
                acc = fmaf(iv[a * 4 + 2], wv_[8 + d], acc);
                acc = fmaf(iv[a * 4 + 3], wv_[12 + d], acc);
                vote[a * 4 + d] = acc;
            }
        }
        if (pass == 0) {
#pragma unroll
            for (int i = 0; i < 16; ++i) un[i] += vote[i];
        } else {
            float l0 = vote[0] * ur[0], l1 = vote[1] * ur[1];
            float l2 = vote[2] * ur[2], l3 = vote[3] * ur[3];
#pragma unroll
            for (int i = 4; i < 16; i += 4) {
                l0 = fmaf(vote[i + 0], ur[i + 0], l0);
                l1 = fmaf(vote[i + 1], ur[i + 1], l1);
                l2 = fmaf(vote[i + 2], ur[i + 2], l2);
                l3 = fmaf(vote[i + 3], ur[i + 3], l3);
            }
            const float lg = ((l0 + l1) + (l2 + l3)) * 0.25f;
            float e = __expf(lg);
            if (ml >= 10) e = 0.f;
            float sm = e;
#pragma unroll
            for (int off2 = 8; off2 >= 1; off2 >>= 1)
                sm += __shfl_xor(sm, off2, 16);
            const float qk = e * __builtin_amdgcn_rcpf(sm * (1.f + 1e-10f));
#pragma unroll
            for (int i = 0; i < 16; ++i) un[i] = fmaf(qk, vote[i], un[i]);
        }
    }

#pragma unroll
    for (int i = 0; i < 16; ++i) {
        un[i] += __shfl_xor(un[i], 16, 64);
        un[i] += __shfl_xor(un[i], 32, 64);
    }
    if ((tid & 63) < 16) {
#pragma unroll
        for (int i = 0; i < 16; ++i) s_red[wv][ml][i] = un[i];
    }
    __syncthreads();
    {
        const int mlf = tid >> 4, i = tid & 15;
        const float s = s_red[0][mlf][i] + s_red[1][mlf][i]
                      + s_red[2][mlf][i] + s_red[3][mlf][i];
        pout[(blk * 16 + mlf) * 16 + i] = s;
    }
}

// fc_final: combine the last pass's partial, LN, write out.
__global__ __launch_bounds__(256) void fc_final(
    const float* __restrict__ pA,    // partial written by even passes
    const float* __restrict__ pB,    // partial written by odd passes
    const float* __restrict__ ln2g,
    const float* __restrict__ ln2b,
    const int*   __restrict__ nroute,
    float* __restrict__ out)         // [64][10][16]
{
    const int R = *nroute;
    const float* P = ((R - 1) & 1) ? pB : pA;
    const int b = blockIdx.x;
    const int tid = threadIdx.x;
    const int i = tid & 15, ml = tid >> 4;

    float s = 0.f;
#pragma unroll
    for (int c = 0; c < 8; ++c)
        s += P[((b * 8 + c) * 16 + ml) * 16 + i];
    if (R == 1) s *= 0.1f;

    float mu = s;
#pragma unroll
    for (int off = 8; off >= 1; off >>= 1) mu += __shfl_xor(mu, off, 16);
    mu *= (1.f / 16.f);
    const float d0 = s - mu;
    float var = d0 * d0;
#pragma unroll
    for (int off = 8; off >= 1; off >>= 1) var += __shfl_xor(var, off, 16);
    var *= (1.f / 16.f);
    const float r = (s - mu) * rsqrtf(var + LN_EPS) * ln2g[i] + ln2b[i];

    if (ml < 10) out[(b * 10 + ml) * 16 + i] = r;
}

// ---------------- fallback 6-launch fc kernels (proven R14 path) ----------------
__global__ __launch_bounds__(256, 4) void fc_partial(
    const float* __restrict__ fcin, const float* __restrict__ wT2b,
    const float* __restrict__ u, const int* __restrict__ nroute,
    const int pass, float* __restrict__ partial)
{
    __shared__ float s_red[4][16][17];
    const int R = *nroute;
    if (pass >= R) return;
    const int blk = blockIdx.x;
    const int b = blk >> 3, c = blk & 7;
    const int tid = threadIdx.x;
    const int ml = tid & 15, grp = tid >> 4;
    const int wv = tid >> 6;
    const float* fb = fcin + (b * 1568 + c * 196) * 16;
    const float* wb = wT2b + (c * 196 * 16) * 16;

    float un[16];
#pragma unroll
    for (int i = 0; i < 16; ++i) un[i] = 0.f;
    float ur[16];
    if (pass) {
#pragma unroll
        for (int q = 0; q < 4; ++q)
            *(float4*)(&ur[q * 4]) = *(const float4*)(u + (b * 16 + ml) * 16 + q * 4);
    }
    for (int t = 0; t < 13; ++t) {
        const int off = t * 16 + grp;
        if (off >= 196) break;
        float iv[16], wv_[16];
        const float* ip = fb + off * 16;
        const float* wp = wb + (off * 16 + ml) * 16;
#pragma unroll
        for (int q = 0; q < 4; ++q) {
            *(float4*)(&iv[q * 4]) = *(const float4*)(ip + q * 4);
            *(float4*)(&wv_[q * 4]) = *(const float4*)(wp + q * 4);
        }
        float vote[16];
#pragma unroll
        for (int a = 0; a < 4; ++a) {
#pragma unroll
            for (int d = 0; d < 4; ++d) {
                float acc = iv[a * 4 + 0] * wv_[0 + d];
                acc = fmaf(iv[a * 4 + 1], wv_[4 + d], acc);
                acc = fmaf(iv[a * 4 + 2], wv_[8 + d], acc);
                acc = fmaf(iv[a * 4 + 3], wv_[12 + d], acc);
                vote[a * 4 + d] = acc;
            }
        }
        if (pass == 0) {
#pragma unroll
            for (int i = 0; i < 16; ++i) un[i] += vote[i];
        } else {
            float l0 = vote[0] * ur[0], l1 = vote[1] * ur[1];
            float l2 = vote[2] * ur[2], l3 = vote[3] * ur[3];
#pragma unroll
            for (int i = 4; i < 16; i += 4) {
                l0 = fmaf(vote[i + 0], ur[i + 0], l0);
                l1 = fmaf(vote[i + 1], ur[i + 1], l1);
                l2 = fmaf(vote[i + 2], ur[i + 2], l2);
                l3 = fmaf(vote[i + 3], ur[i + 3], l3);
            }
            const float lg = ((l0 + l1) + (l2 + l3)) * 0.25f;
            float e = __expf(lg);
            if (ml >= 10) e = 0.f;
            float sm = e;
#pragma unroll
            for (int off2 = 8; off2 >= 1; off2 >>= 1)
                sm += __shfl_xor(sm, off2, 16);
            const float qk = e * __builtin_amdgcn_rcpf(sm * (1.f + 1e-10f));
#pragma unroll
            for (int i = 0; i < 16; ++i) un[i] = fmaf(qk, vote[i], un[i]);
        }
    }
#pragma unroll
    for (int i = 0; i < 16; ++i) {
        un[i] += __shfl_xor(un[i], 16, 64);
        un[i] += __shfl_xor(un[i], 32, 64);
    }
    if ((tid & 63) < 16) {
#pragma unroll
        for (int i = 0; i < 16; ++i) s_red[wv][ml][i] = un[i];
    }
    __syncthreads();
    {
        const int mlf = tid >> 4, i = tid & 15;
        const float s = s_red[0][mlf][i] + s_red[1][mlf][i]
                      + s_red[2][mlf][i] + s_red[3][mlf][i];
        partial[(blk * 16 + mlf) * 16 + i] = s;
    }
}

__global__ __launch_bounds__(256) void fc_combine(
    const float* __restrict__ partial, const float* __restrict__ ln2g,
    const float* __restrict__ ln2b, const int* __restrict__ nroute,
    const int pass, float* __restrict__ u, float* __restrict__ out)
{
    const int R = *nroute;
    if (pass >= R) return;
    const int b = blockIdx.x;
    const int tid = threadIdx.x;
    const int i = tid & 15, ml = tid >> 4;
    float s = 0.f;
#pragma unroll
    for (int c = 0; c < 8; ++c)
        s += partial[((b * 8 + c) * 16 + ml) * 16 + i];
    if (pass == 0) s *= 0.1f;
    float mu = s;
#pragma unroll
    for (int off = 8; off >= 1; off >>= 1) mu += __shfl_xor(mu, off, 16);
    mu *= (1.f / 16.f);
    const float d0 = s - mu;
    float var = d0 * d0;
#pragma unroll
    for (int off = 8; off >= 1; off >>= 1) var += __shfl_xor(var, off, 16);
    var *= (1.f / 16.f);
    const float r = (s - mu) * rsqrtf(var + LN_EPS) * ln2g[i] + ln2b[i];
    u[(b * 16 + ml) * 16 + i] = r;
    if (pass == R - 1 && ml < 10) out[(b * 10 + ml) * 16 + i] = r;
}

extern "C" void kernel_launch(void* const* d_in, const int* in_sizes, int n_in,
                              void* d_out, int out_size, void* d_ws, size_t ws_size,
                              hipStream_t stream) {
    const float* x     = (const float*)d_in[0];
    const float* wconv = (const float*)d_in[1];
    const float* wfc   = (const float*)d_in[2];
    const float* ln1g  = (const float*)d_in[3];
    const float* ln1b  = (const float*)d_in[4];
    const float* ln2g  = (const float*)d_in[5];
    const float* ln2b  = (const float*)d_in[6];
    const int*   nrt   = (const int*)d_in[7];
    float* out = (float*)d_out;

    float* vout = (float*)d_ws;                                  // 6,422,528 B

    if (ws_size >= 9076736) {
        // new layout: wT2b | pA (wTh aliases its head; dead after conv) | pB
        float* wT2b = (float*)((char*)d_ws + 6422528);           // 1,605,632 B
        float* pA   = (float*)((char*)d_ws + 8028160);           // 524,288 B
        float* pB   = (float*)((char*)d_ws + 8552448);           // 524,288 B
        unsigned short* wTh = (unsigned short*)pA;               // 294,912 B alias

        hipLaunchKernelGGL(transpose_weights, dim3(2144), dim3(256), 0, stream,
                           wconv, wfc, wTh, wT2b);
        hipLaunchKernelGGL(conv_routing_kernel, dim3(784), dim3(256), 0, stream,
                           x, wTh, ln1g, ln1b, nrt, vout);
        hipLaunchKernelGGL(fc_pass, dim3(512), dim3(256), 0, stream,
                           vout, wT2b, (const float*)nullptr, ln2g, ln2b, nrt, 0, pA);
        hipLaunchKernelGGL(fc_pass, dim3(512), dim3(256), 0, stream,
                           vout, wT2b, (const float*)pA, ln2g, ln2b, nrt, 1, pB);
        hipLaunchKernelGGL(fc_pass, dim3(512), dim3(256), 0, stream,
                           vout, wT2b, (const float*)pB, ln2g, ln2b, nrt, 2, pA);
        hipLaunchKernelGGL(fc_final, dim3(64), dim3(256), 0, stream,
                           pA, pB, ln2g, ln2b, nrt, out);
    } else {
        // fallback: R14's proven tight layout, 6-launch fc
        unsigned short* wTh = (unsigned short*)((char*)d_ws + 6422528);
        float* wT2b    = (float*)((char*)d_ws + 6422528);        // aliases wTh
        float* ubuf    = (float*)((char*)d_ws + 8028160);        // 65,536 B
        float* partial = (float*)((char*)d_ws + 8093696);        // 524,288 B

        hipLaunchKernelGGL(transpose_wconv, dim3(576), dim3(256), 0, stream,
                           wconv, wTh);
        hipLaunchKernelGGL(conv_routing_kernel, dim3(784), dim3(256), 0, stream,
                           x, wTh, ln1g, ln1b, nrt, vout);
        hipLaunchKernelGGL(transpose_wfc, dim3(1568), dim3(256), 0, stream,
                           wfc, wT2b);
        for (int pass = 0; pass < 3; ++pass) {
            hipLaunchKernelGGL(fc_partial, dim3(512), dim3(256), 0, stream,
                               vout, wT2b, ubuf, nrt, pass, partial);
            hipLaunchKernelGGL(fc_combine, dim3(64), dim3(256), 0, stream,
                               partial, ln2g, ln2b, nrt, pass, ubuf, out);
        }
    }
}

// Round 4
// 314.826 us; speedup vs baseline: 3.5334x; 3.5334x over previous
//
#include <hip/hip_runtime.h>
#include <hip/hip_bf16.h>

// CapsModel: B=64 N=32 H=W=16 A=16 K=3 stride=2 -> Ho=Wo=7, M=32, SD=4, D=16
// R20: RECOVERY. conv routing reverted to R17 exactly (proven 218us conv /
//   307us total: one site per block, 3136 x 256 thr, t-PAIRS, (256,4),
//   VGPR 52, zero spill), plus ONE local change: hoist the loop-invariant
//   s_v[m][*] reads (routing state) out of the t-pair loop into registers
//   (vrr[16]). Was 16 ds_read_b32 per j x 18 j x 2 passes per thread.
//   MFMA experiments R18 (306us: barrier/latency-bound) and R19 (1043us:
//   664MB scratch spill + 4x B-fetch) both lost to this VALU structure --
//   do not revisit without disasm evidence.
// fc routing R16: 4 launches, prev-partial double-buffered. Unchanged.

#define LN_EPS 1e-5f

typedef _Float16 h2 __attribute__((ext_vector_type(2)));

__device__ __forceinline__ unsigned packh2(float a, float b) {
    const unsigned short ua = __builtin_bit_cast(unsigned short, (_Float16)a);
    const unsigned short ub = __builtin_bit_cast(unsigned short, (_Float16)b);
    return (unsigned)ua | ((unsigned)ub << 16);
}

__device__ __forceinline__ float fdot2u(unsigned a, unsigned b, float c) {
#if __has_builtin(__builtin_amdgcn_fdot2)
    return __builtin_amdgcn_fdot2(__builtin_bit_cast(h2, a),
                                  __builtin_bit_cast(h2, b), c, false);
#else
    const h2 ha = __builtin_bit_cast(h2, a), hb = __builtin_bit_cast(h2, b);
    return fmaf((float)ha.x, (float)hb.x, fmaf((float)ha.y, (float)hb.y, c));
#endif
}

// ---------------- weight transposes ----------------
// wTh [288][32][16] f16: row r = n*9+kl; inner idx = d*4+x (x-pairs adjacent).
__global__ __launch_bounds__(256) void transpose_wconv(
    const float* __restrict__ wconv, unsigned short* __restrict__ wTh)
{
    const int i = blockIdx.x * 256 + threadIdx.x;
    if (i < 147456) {
        const int x = i & 3, d = (i >> 2) & 3, mm = (i >> 4) & 31, r = i >> 9;
        const int n = r / 9, kl = r % 9;
        const float v = wconv[((kl * 32 + n) * 16 + x * 4 + d) * 32 + mm];
        wTh[i] = __builtin_bit_cast(unsigned short, (_Float16)v);
    }
}
// wT2b [1568][16][16] fp32: [n][m (pad 10->16, zeros)][x*4+d]
__global__ __launch_bounds__(256) void transpose_wfc(
    const float* __restrict__ wfc, float* __restrict__ wT2b)
{
    const int j = blockIdx.x * 256 + threadIdx.x;
    if (j < 401408) {
        const int xd = j & 15, mm = (j >> 4) & 15, n = j >> 8;
        const int x = xd >> 2, dd = xd & 3;
        wT2b[j] = (mm < 10) ? wfc[((n * 4 + x) * 4 + dd) * 10 + mm] : 0.f;
    }
}
// fused (roomy ws layout)
__global__ __launch_bounds__(256) void transpose_weights(
    const float* __restrict__ wconv, const float* __restrict__ wfc,
    unsigned short* __restrict__ wTh, float* __restrict__ wT2b)
{
    const int blk = blockIdx.x;
    if (blk < 576) {
        const int i = blk * 256 + threadIdx.x;
        if (i < 147456) {
            const int x = i & 3, d = (i >> 2) & 3, mm = (i >> 4) & 31, r = i >> 9;
            const int n = r / 9, kl = r % 9;
            const float v = wconv[((kl * 32 + n) * 16 + x * 4 + d) * 32 + mm];
            wTh[i] = __builtin_bit_cast(unsigned short, (_Float16)v);
        }
    } else {
        const int j = (blk - 576) * 256 + threadIdx.x;
        if (j < 401408) {
            const int xd = j & 15, mm = (j >> 4) & 15, n = j >> 8;
            const int x = xd >> 2, dd = xd & 3;
            wT2b[j] = (mm < 10) ? wfc[((n * 4 + x) * 4 + dd) * 10 + mm] : 0.f;
        }
    }
}

// ---------------- Stage 1: conv routing (R17 structure) ----------------
__global__ __launch_bounds__(256, 4) void conv_routing_kernel(
    const float* __restrict__ x,             // [64][32][16][16][16]
    const unsigned short* __restrict__ wTh,  // [288][32][16] f16
    const float* __restrict__ ln1g,
    const float* __restrict__ ln1b,
    const int*   __restrict__ nroute,
    float* __restrict__ vout)                // [64][32][49][16]
{
    __shared__ unsigned short s_inp[288][16];  // f16 x-pairs, 9,216 B
    __shared__ float s_v[32][17];              // 2,176 B
    __shared__ float s_red[2][32][17];         // 4,352 B  => 15,744 B total

    const int tid = threadIdx.x;
    const int m   = tid & 31;
    const int g   = (tid >> 5) & 7;  // 0..7
    const int lw  = tid >> 6;        // 0..3
    const int site = blockIdx.x;
    const int b = site / 49, hw = site % 49;
    const int h = hw / 7, w = hw % 7;

    // stage inp (coalesced float4 loads, f16 pack); row = n*9+kl
    for (int i = tid; i < 1152; i += 256) {    // 288 rows * 4 quads
        const int row = i >> 2, q = i & 3;
        const int n = row / 9, kl = row % 9;
        const int k = kl / 3, l = kl % 3;
        const float4 val = *(const float4*)(
            x + ((((b * 32 + n) * 16 + (2 * h + k)) * 16 + (2 * w + l)) * 16 + q * 4));
        uint2 p;
        p.x = packh2(val.x, val.y);
        p.y = packh2(val.z, val.w);
        *(uint2*)(&s_inp[row][q * 4]) = p;
    }
    __syncthreads();

    const int R = *nroute;
    const int nkl0 = g * 36;
    const unsigned short* const wp0 = wTh + (nkl0 * 32 + m) * 16;

    for (int pass = 0; pass < R; ++pass) {
        float vn[16];
#pragma unroll
        for (int i = 0; i < 16; ++i) vn[i] = 0.f;

        if (pass == 0) {
            const unsigned short* wp = wp0;
            for (int t = 0; t < 36; ++t, wp += 512) {
                const uint4 wa = *(const uint4*)(wp);
                const uint4 wb = *(const uint4*)(wp + 8);
                const unsigned wu[8] = { wa.x, wa.y, wa.z, wa.w, wb.x, wb.y, wb.z, wb.w };
                const uint4* rp = (const uint4*)(&s_inp[nkl0 + t][0]);
                const uint4 ua = rp[0], ub = rp[1];
                const unsigned iu[8] = { ua.x, ua.y, ua.z, ua.w, ub.x, ub.y, ub.z, ub.w };
#pragma unroll
                for (int a = 0; a < 4; ++a) {
#pragma unroll
                    for (int d = 0; d < 4; ++d) {
                        vn[a * 4 + d] = fdot2u(iu[a * 2], wu[d * 2],
                            fdot2u(iu[a * 2 + 1], wu[d * 2 + 1], vn[a * 4 + d]));
                    }
                }
            }
        } else {
            // R20: hoist loop-invariant routing state s_v[m][*] into regs
            // (was re-read from LDS every j-iteration).
            float vrr[16];
#pragma unroll
            for (int i = 0; i < 16; ++i) vrr[i] = s_v[m][i];

            const unsigned short* wp = wp0;
            for (int j = 0; j < 18; ++j, wp += 1024) {   // t-pairs
                const uint4 wa0 = *(const uint4*)(wp);
                const uint4 wb0 = *(const uint4*)(wp + 8);
                const uint4 wa1 = *(const uint4*)(wp + 512);
                const uint4 wb1 = *(const uint4*)(wp + 520);
                const unsigned wu0[8] = { wa0.x, wa0.y, wa0.z, wa0.w, wb0.x, wb0.y, wb0.z, wb0.w };
                const unsigned wu1[8] = { wa1.x, wa1.y, wa1.z, wa1.w, wb1.x, wb1.y, wb1.z, wb1.w };
                const uint4* rp0 = (const uint4*)(&s_inp[nkl0 + 2 * j][0]);
                const uint4* rp1 = (const uint4*)(&s_inp[nkl0 + 2 * j + 1][0]);
                const uint4 ua0 = rp0[0], ub0 = rp0[1];
                const uint4 ua1 = rp1[0], ub1 = rp1[1];
                const unsigned iu0[8] = { ua0.x, ua0.y, ua0.z, ua0.w, ub0.x, ub0.y, ub0.z, ub0.w };
                const unsigned iu1[8] = { ua1.x, ua1.y, ua1.z, ua1.w, ub1.x, ub1.y, ub1.z, ub1.w };

                float uh0[16], uh1[16];
#pragma unroll
                for (int a = 0; a < 4; ++a) {
#pragma unroll
                    for (int d = 0; d < 4; ++d) {
                        uh0[a * 4 + d] = fdot2u(iu0[a * 2], wu0[d * 2],
                            fdot2u(iu0[a * 2 + 1], wu0[d * 2 + 1], 0.f));
                        uh1[a * 4 + d] = fdot2u(iu1[a * 2], wu1[d * 2],
                            fdot2u(iu1[a * 2 + 1], wu1[d * 2 + 1], 0.f));
                    }
                }

                float p0 = 0.f, p1 = 0.f, q0 = 0.f, q1 = 0.f;
#pragma unroll
                for (int i = 0; i < 16; i += 2) {
                    const float c0 = vrr[i], c1 = vrr[i + 1];
                    p0 = fmaf(uh0[i], c0, p0);
                    q0 = fmaf(uh0[i + 1], c1, q0);
                    p1 = fmaf(uh1[i], c0, p1);
                    q1 = fmaf(uh1[i + 1], c1, q1);
                }
                const float e0 = __expf((p0 + q0) * 0.25f);
                const float e1 = __expf((p1 + q1) * 0.25f);

                float sm0 = e0, sm1 = e1;
#pragma unroll
                for (int off = 16; off >= 1; off >>= 1) {
                    const float r0 = __shfl_xor(sm0, off, 32);
                    const float r1 = __shfl_xor(sm1, off, 32);
                    sm0 += r0;
                    sm1 += r1;
                }
                const float qk0 = e0 * __builtin_amdgcn_rcpf(sm0 * (1.f + 1e-10f));
                const float qk1 = e1 * __builtin_amdgcn_rcpf(sm1 * (1.f + 1e-10f));
#pragma unroll
                for (int i = 0; i < 16; ++i) {
                    vn[i] = fmaf(qk0, uh0[i], vn[i]);
                    vn[i] = fmaf(qk1, uh1[i], vn[i]);
                }
            }
        }

#pragma unroll
        for (int i = 0; i < 16; ++i) vn[i] += __shfl_xor(vn[i], 32, 64);

        if (lw >= 2) {
#pragma unroll
            for (int i = 0; i < 16; ++i) s_red[lw - 2][m][i] = vn[i];
        }
        __syncthreads();
        if (lw < 2) {
#pragma unroll
            for (int i = 0; i < 16; ++i) vn[i] += s_red[lw][m][i];
            if (lw == 1) {
#pragma unroll
                for (int i = 0; i < 16; ++i) s_red[1][m][i] = vn[i];
            }
        }
        __syncthreads();
        if (lw == 0) {
#pragma unroll
            for (int i = 0; i < 16; ++i) vn[i] += s_red[1][m][i];
            const float scale = pass ? 1.f : (1.f / 32.f);
            float mu = 0.f;
#pragma unroll
            for (int i = 0; i < 16; ++i) { vn[i] *= scale; mu += vn[i]; }
            mu *= (1.f / 16.f);
            float var = 0.f;
#pragma unroll
            for (int i = 0; i < 16; ++i) {
                const float d0 = vn[i] - mu;
                var = fmaf(d0, d0, var);
            }
            var *= (1.f / 16.f);
            const float inv = rsqrtf(var + LN_EPS);
#pragma unroll
            for (int i = 0; i < 16; ++i)
                s_v[m][i] = (vn[i] - mu) * inv * ln1g[i] + ln1b[i];
        }
        __syncthreads();
    }

    for (int p = tid; p < 512; p += 256) {
        const int mm = p >> 4, i = p & 15;
        vout[((b * 32 + mm) * 49 + hw) * 16 + i] = s_v[mm][i];
    }
}

// ---------------- Stage 2: FC routing ----------------
// fc_pass: 512 blocks = 64 b x 8 chunks; 256 thr = 16 grp x 16 ml.
// For pass>=1, each block redundantly recomputes its b's u from the
// previous pass's partial (combine+LN in LDS) - no ubuf, no extra launch.
__global__ __launch_bounds__(256, 4) void fc_pass(
    const float* __restrict__ fcin,  // [64][1568][16]
    const float* __restrict__ wT2b,  // [1568][16][16] ([n][ml][x*4+d])
    const float* __restrict__ prev,  // [512][16][16] partial from pass-1 (or null)
    const float* __restrict__ ln2g,
    const float* __restrict__ ln2b,
    const int*   __restrict__ nroute,
    const int    pass,
    float* __restrict__ pout)        // [512][16][16]
{
    __shared__ float s_red[4][16][17];
    __shared__ float s_u[16][17];

    const int R = *nroute;
    if (pass >= R) return;
    const int blk = blockIdx.x;
    const int b = blk >> 3, c = blk & 7;
    const int tid = threadIdx.x;
    const int ml = tid & 15, grp = tid >> 4;
    const int wv = tid >> 6;

    float ur[16];
    if (pass) {
        // inline combine + LN: thread (mlf, ii)
        const int mlf = tid >> 4, ii = tid & 15;
        float s = 0.f;
#pragma unroll
        for (int c2 = 0; c2 < 8; ++c2)
            s += prev[((b * 8 + c2) * 16 + mlf) * 16 + ii];
        if (pass == 1) s *= 0.1f;   // pass-0 output carries the 1/Cls scale
        float mu = s;
#pragma unroll
        for (int off = 8; off >= 1; off >>= 1) mu += __shfl_xor(mu, off, 16);
        mu *= (1.f / 16.f);
        const float d0 = s - mu;
        float var = d0 * d0;
#pragma unroll
        for (int off = 8; off >= 1; off >>= 1) var += __shfl_xor(var, off, 16);
        var *= (1.f / 16.f);
        s_u[mlf][ii] = (s - mu) * rsqrtf(var + LN_EPS) * ln2g[ii] + ln2b[ii];
        __syncthreads();
#pragma unroll
        for (int i = 0; i < 16; ++i) ur[i] = s_u[ml][i];
    }

    const float* fb = fcin + (b * 1568 + c * 196) * 16;
    const float* wb = wT2b + (c * 196 * 16) * 16;

    float un[16];
#pragma unroll
    for (int i = 0; i < 16; ++i) un[i] = 0.f;

    for (int t = 0; t < 13; ++t) {
        const int off = t * 16 + grp;
        if (off >= 196) break;
        float iv[16], wv_[16];
        const float* ip = fb + off * 16;
        const float* wp = wb + (off * 16 + ml) * 16;
#pragma unroll
        for (int q = 0; q < 4; ++q) {
            *(float4*)(&iv[q * 4]) = *(const float4*)(ip + q * 4);
            *(float4*)(&wv_[q * 4]) = *(const float4*)(wp + q * 4);
        }
        float vote[16];
#pragma unroll
        for (int a = 0; a < 4; ++a) {
#pragma unroll
            for (int d = 0; d < 4; ++d) {
                float acc = iv[a * 4 + 0] * wv_[0 + d];
                acc = fmaf(iv[a * 4 + 1], wv_[4 + d], acc);
                acc = fmaf(iv[a * 4 + 2], wv_[8 + d], acc);
                acc = fmaf(iv[a * 4 + 3], wv_[12 + d], acc);
                vote[a * 4 + d] = acc;
            }
        }
        if (pass == 0) {
#pragma unroll
            for (int i = 0; i < 16; ++i) un[i] += vote[i];
        } else {
            float l0 = vote[0] * ur[0], l1 = vote[1] * ur[1];
            float l2 = vote[2] * ur[2], l3 = vote[3] * ur[3];
#pragma unroll
            for (int i = 4; i < 16; i += 4) {
                l0 = fmaf(vote[i + 0], ur[i + 0], l0);
                l1 = fmaf(vote[i + 1], ur[i + 1], l1);
                l2 = fmaf(vote[i + 2], ur[i + 2], l2);
                l3 = fmaf(vote[i + 3], ur[i + 3], l3);
            }
            const float lg = ((l0 + l1) + (l2 + l3)) * 0.25f;
            float e = __expf(lg);
            if (ml >= 10) e = 0.f;
            float sm = e;
#pragma unroll
            for (int off2 = 8; off2 >= 1; off2 >>= 1)
                sm += __shfl_xor(sm, off2, 16);
            const float qk = e * __builtin_amdgcn_rcpf(sm * (1.f + 1e-10f));
#pragma unroll
            for (int i = 0; i < 16; ++i) un[i] = fmaf(qk, vote[i], un[i]);
        }
    }

#pragma unroll
    for (int i = 0; i < 16; ++i) {
        un[i] += __shfl_xor(un[i], 16, 64);
        un[i] += __shfl_xor(un[i], 32, 64);
    }
    if ((tid & 63) < 16) {
#pragma unroll
        for (int i = 0; i < 16; ++i) s_red[wv][ml][i] = un[i];
    }
    __syncthreads();
    {
        const int mlf = tid >> 4, i = tid & 15;
        const float s = s_red[0][mlf][i] + s_red[1][mlf][i]
                      + s_red[2][mlf][i] + s_red[3][mlf][i];
        pout[(blk * 16 + mlf) * 16 + i] = s;
    }
}

// fc_final: combine the last pass's partial, LN, write out.
__global__ __launch_bounds__(256) void fc_final(
    const float* __restrict__ pA,    // partial written by even passes
    const float* __restrict__ pB,    // partial written by odd passes
    const float* __restrict__ ln2g,
    const float* __restrict__ ln2b,
    const int*   __restrict__ nroute,
    float* __restrict__ out)         // [64][10][16]
{
    const int R = *nroute;
    const float* P = ((R - 1) & 1) ? pB : pA;
    const int b = blockIdx.x;
    const int tid = threadIdx.x;
    const int i = tid & 15, ml = tid >> 4;

    float s = 0.f;
#pragma unroll
    for (int c = 0; c < 8; ++c)
        s += P[((b * 8 + c) * 16 + ml) * 16 + i];
    if (R == 1) s *= 0.1f;

    float mu = s;
#pragma unroll
    for (int off = 8; off >= 1; off >>= 1) mu += __shfl_xor(mu, off, 16);
    mu *= (1.f / 16.f);
    const float d0 = s - mu;
    float var = d0 * d0;
#pragma unroll
    for (int off = 8; off >= 1; off >>= 1) var += __shfl_xor(var, off, 16);
    var *= (1.f / 16.f);
    const float r = (s - mu) * rsqrtf(var + LN_EPS) * ln2g[i] + ln2b[i];

    if (ml < 10) out[(b * 10 + ml) * 16 + i] = r;
}

// ---------------- fallback 6-launch fc kernels (proven R14 path) ----------------
__global__ __launch_bounds__(256, 4) void fc_partial(
    const float* __restrict__ fcin, const float* __restrict__ wT2b,
    const float* __restrict__ u, const int* __restrict__ nroute,
    const int pass, float* __restrict__ partial)
{
    __shared__ float s_red[4][16][17];
    const int R = *nroute;
    if (pass >= R) return;
    const int blk = blockIdx.x;
    const int b = blk >> 3, c = blk & 7;
    const int tid = threadIdx.x;
    const int ml = tid & 15, grp = tid >> 4;
    const int wv = tid >> 6;
    const float* fb = fcin + (b * 1568 + c * 196) * 16;
    const float* wb = wT2b + (c * 196 * 16) * 16;

    float un[16];
#pragma unroll
    for (int i = 0; i < 16; ++i) un[i] = 0.f;
    float ur[16];
    if (pass) {
#pragma unroll
        for (int q = 0; q < 4; ++q)
            *(float4*)(&ur[q * 4]) = *(const float4*)(u + (b * 16 + ml) * 16 + q * 4);
    }
    for (int t = 0; t < 13; ++t) {
        const int off = t * 16 + grp;
        if (off >= 196) break;
        float iv[16], wv_[16];
        const float* ip = fb + off * 16;
        const float* wp = wb + (off * 16 + ml) * 16;
#pragma unroll
        for (int q = 0; q < 4; ++q) {
            *(float4*)(&iv[q * 4]) = *(const float4*)(ip + q * 4);
            *(float4*)(&wv_[q * 4]) = *(const float4*)(wp + q * 4);
        }
        float vote[16];
#pragma unroll
        for (int a = 0; a < 4; ++a) {
#pragma unroll
            for (int d = 0; d < 4; ++d) {
                float acc = iv[a * 4 + 0] * wv_[0 + d];
                acc = fmaf(iv[a * 4 + 1], wv_[4 + d], acc);
                acc = fmaf(iv[a * 4 + 2], wv_[8 + d], acc);
                acc = fmaf(iv[a * 4 + 3], wv_[12 + d], acc);
                vote[a * 4 + d] = acc;
            }
        }
        if (pass == 0) {
#pragma unroll
            for (int i = 0; i < 16; ++i) un[i] += vote[i];
        } else {
            float l0 = vote[0] * ur[0], l1 = vote[1] * ur[1];
            float l2 = vote[2] * ur[2], l3 = vote[3] * ur[3];
#pragma unroll
            for (int i = 4; i < 16; i += 4) {
                l0 = fmaf(vote[i + 0], ur[i + 0], l0);
                l1 = fmaf(vote[i + 1], ur[i + 1], l1);
                l2 = fmaf(vote[i + 2], ur[i + 2], l2);
                l3 = fmaf(vote[i + 3], ur[i + 3], l3);
            }
            const float lg = ((l0 + l1) + (l2 + l3)) * 0.25f;
            float e = __expf(lg);
            if (ml >= 10) e = 0.f;
            float sm = e;
#pragma unroll
            for (int off2 = 8; off2 >= 1; off2 >>= 1)
                sm += __shfl_xor(sm, off2, 16);
            const float qk = e * __builtin_amdgcn_rcpf(sm * (1.f + 1e-10f));
#pragma unroll
            for (int i = 0; i < 16; ++i) un[i] = fmaf(qk, vote[i], un[i]);
        }
    }
#pragma unroll
    for (int i = 0; i < 16; ++i) {
        un[i] += __shfl_xor(un[i], 16, 64);
        un[i] += __shfl_xor(un[i], 32, 64);
    }
    if ((tid & 63) < 16) {
#pragma unroll
        for (int i = 0; i < 16; ++i) s_red[wv][ml][i] = un[i];
    }
    __syncthreads();
    {
        const int mlf = tid >> 4, i = tid & 15;
        const float s = s_red[0][mlf][i] + s_red[1][mlf][i]
                      + s_red[2][mlf][i] + s_red[3][mlf][i];
        partial[(blk * 16 + mlf) * 16 + i] = s;
    }
}

__global__ __launch_bounds__(256) void fc_combine(
    const float* __restrict__ partial, const float* __restrict__ ln2g,
    const float* __restrict__ ln2b, const int* __restrict__ nroute,
    const int pass, float* __restrict__ u, float* __restrict__ out)
{
    const int R = *nroute;
    if (pass >= R) return;
    const int b = blockIdx.x;
    const int tid = threadIdx.x;
    const int i = tid & 15, ml = tid >> 4;
    float s = 0.f;
#pragma unroll
    for (int c = 0; c < 8; ++c)
        s += partial[((b * 8 + c) * 16 + ml) * 16 + i];
    if (pass == 0) s *= 0.1f;
    float mu = s;
#pragma unroll
    for (int off = 8; off >= 1; off >>= 1) mu += __shfl_xor(mu, off, 16);
    mu *= (1.f / 16.f);
    const float d0 = s - mu;
    float var = d0 * d0;
#pragma unroll
    for (int off = 8; off >= 1; off >>= 1) var += __shfl_xor(var, off, 16);
    var *= (1.f / 16.f);
    const float r = (s - mu) * rsqrtf(var + LN_EPS) * ln2g[i] + ln2b[i];
    u[(b * 16 + ml) * 16 + i] = r;
    if (pass == R - 1 && ml < 10) out[(b * 10 + ml) * 16 + i] = r;
}

extern "C" void kernel_launch(void* const* d_in, const int* in_sizes, int n_in,
                              void* d_out, int out_size, void* d_ws, size_t ws_size,
                              hipStream_t stream) {
    const float* x     = (const float*)d_in[0];
    const float* wconv = (const float*)d_in[1];
    const float* wfc   = (const float*)d_in[2];
    const float* ln1g  = (const float*)d_in[3];
    const float* ln1b  = (const float*)d_in[4];
    const float* ln2g  = (const float*)d_in[5];
    const float* ln2b  = (const float*)d_in[6];
    const int*   nrt   = (const int*)d_in[7];
    float* out = (float*)d_out;

    float* vout = (float*)d_ws;                                  // 6,422,528 B

    if (ws_size >= 9076736) {
        // new layout: wT2b | pA (wTh aliases its head; dead after conv) | pB
        float* wT2b = (float*)((char*)d_ws + 6422528);           // 1,605,632 B
        float* pA   = (float*)((char*)d_ws + 8028160);           // 524,288 B
        float* pB   = (float*)((char*)d_ws + 8552448);           // 524,288 B
        unsigned short* wTh = (unsigned short*)pA;               // 294,912 B alias

        hipLaunchKernelGGL(transpose_weights, dim3(2144), dim3(256), 0, stream,
                           wconv, wfc, wTh, wT2b);
        hipLaunchKernelGGL(conv_routing_kernel, dim3(3136), dim3(256), 0, stream,
                           x, wTh, ln1g, ln1b, nrt, vout);
        hipLaunchKernelGGL(fc_pass, dim3(512), dim3(256), 0, stream,
                           vout, wT2b, (const float*)nullptr, ln2g, ln2b, nrt, 0, pA);
        hipLaunchKernelGGL(fc_pass, dim3(512), dim3(256), 0, stream,
                           vout, wT2b, (const float*)pA, ln2g, ln2b, nrt, 1, pB);
        hipLaunchKernelGGL(fc_pass, dim3(512), dim3(256), 0, stream,
                           vout, wT2b, (const float*)pB, ln2g, ln2b, nrt, 2, pA);
        hipLaunchKernelGGL(fc_final, dim3(64), dim3(256), 0, stream,
                           pA, pB, ln2g, ln2b, nrt, out);
    } else {
        // fallback: R14's proven tight layout, 6-launch fc
        unsigned short* wTh = (unsigned short*)((char*)d_ws + 6422528);
        float* wT2b    = (float*)((char*)d_ws + 6422528);        // aliases wTh
        float* ubuf    = (float*)((char*)d_ws + 8028160);        // 65,536 B
        float* partial = (float*)((char*)d_ws + 8093696);        // 524,288 B

        hipLaunchKernelGGL(transpose_wconv, dim3(576), dim3(256), 0, stream,
                           wconv, wTh);
        hipLaunchKernelGGL(conv_routing_kernel, dim3(3136), dim3(256), 0, stream,
                           x, wTh, ln1g, ln1b, nrt, vout);
        hipLaunchKernelGGL(transpose_wfc, dim3(1568), dim3(256), 0, stream,
                           wfc, wT2b);
        for (int pass = 0; pass < 3; ++pass) {
            hipLaunchKernelGGL(fc_partial, dim3(512), dim3(256), 0, stream,
                               vout, wT2b, ubuf, nrt, pass, partial);
            hipLaunchKernelGGL(fc_combine, dim3(64), dim3(256), 0, stream,
                               partial, ln2g, ln2b, nrt, pass, ubuf, out);
        }
    }
}

// Round 5
// 311.479 us; speedup vs baseline: 3.5713x; 1.0107x over previous
//
#include <hip/hip_runtime.h>
#include <hip/hip_bf16.h>

// CapsModel: B=64 N=32 H=W=16 A=16 K=3 stride=2 -> Ho=Wo=7, M=32, SD=4, D=16
// R21: R20 structure (proven 220us conv), ONE change: fdot2u now emits
//   v_dot2_f32_f16 via inline asm unconditionally.
//   Evidence: measured 16.4K VALU issues/wave vs ~7K source-level if dot2
//   is a single instruction; the gap matches the cvt+fma fallback expansion
//   (4+ VALU/call) almost exactly => __builtin_amdgcn_fdot2 was not taken.
//   Prediction: conv 220 -> 100-140us. If conv stays ~220, theory is wrong
//   (inflation elsewhere) -> pull disasm next. If assembler rejects dot2,
//   revert + manual cvt-hoist formulation.
// conv structure: one site per block, 3136 x 256 thr, t-PAIRS, (256,4),
//   VGPR 52, zero spill. MFMA rewrites R18 (latency-bound, 306us) and
//   R19 (spill, 1043us) both lost to this -- do not revisit w/o disasm.
// fc routing R16: 4 launches, prev-partial double-buffered. Unchanged.

#define LN_EPS 1e-5f

typedef _Float16 h2 __attribute__((ext_vector_type(2)));

__device__ __forceinline__ unsigned packh2(float a, float b) {
    const unsigned short ua = __builtin_bit_cast(unsigned short, (_Float16)a);
    const unsigned short ub = __builtin_bit_cast(unsigned short, (_Float16)b);
    return (unsigned)ua | ((unsigned)ub << 16);
}

// R21: force v_dot2_f32_f16 (f32 += a.lo*b.lo + a.hi*b.hi, f16 inputs).
__device__ __forceinline__ float fdot2u(unsigned a, unsigned b, float c) {
    float d;
    asm("v_dot2_f32_f16 %0, %1, %2, %3" : "=v"(d) : "v"(a), "v"(b), "v"(c));
    return d;
}

// ---------------- weight transposes ----------------
// wTh [288][32][16] f16: row r = n*9+kl; inner idx = d*4+x (x-pairs adjacent).
__global__ __launch_bounds__(256) void transpose_wconv(
    const float* __restrict__ wconv, unsigned short* __restrict__ wTh)
{
    const int i = blockIdx.x * 256 + threadIdx.x;
    if (i < 147456) {
        const int x = i & 3, d = (i >> 2) & 3, mm = (i >> 4) & 31, r = i >> 9;
        const int n = r / 9, kl = r % 9;
        const float v = wconv[((kl * 32 + n) * 16 + x * 4 + d) * 32 + mm];
        wTh[i] = __builtin_bit_cast(unsigned short, (_Float16)v);
    }
}
// wT2b [1568][16][16] fp32: [n][m (pad 10->16, zeros)][x*4+d]
__global__ __launch_bounds__(256) void transpose_wfc(
    const float* __restrict__ wfc, float* __restrict__ wT2b)
{
    const int j = blockIdx.x * 256 + threadIdx.x;
    if (j < 401408) {
        const int xd = j & 15, mm = (j >> 4) & 15, n = j >> 8;
        const int x = xd >> 2, dd = xd & 3;
        wT2b[j] = (mm < 10) ? wfc[((n * 4 + x) * 4 + dd) * 10 + mm] : 0.f;
    }
}
// fused (roomy ws layout)
__global__ __launch_bounds__(256) void transpose_weights(
    const float* __restrict__ wconv, const float* __restrict__ wfc,
    unsigned short* __restrict__ wTh, float* __restrict__ wT2b)
{
    const int blk = blockIdx.x;
    if (blk < 576) {
        const int i = blk * 256 + threadIdx.x;
        if (i < 147456) {
            const int x = i & 3, d = (i >> 2) & 3, mm = (i >> 4) & 31, r = i >> 9;
            const int n = r / 9, kl = r % 9;
            const float v = wconv[((kl * 32 + n) * 16 + x * 4 + d) * 32 + mm];
            wTh[i] = __builtin_bit_cast(unsigned short, (_Float16)v);
        }
    } else {
        const int j = (blk - 576) * 256 + threadIdx.x;
        if (j < 401408) {
            const int xd = j & 15, mm = (j >> 4) & 15, n = j >> 8;
            const int x = xd >> 2, dd = xd & 3;
            wT2b[j] = (mm < 10) ? wfc[((n * 4 + x) * 4 + dd) * 10 + mm] : 0.f;
        }
    }
}

// ---------------- Stage 1: conv routing (R17 structure + dot2 asm) ----------------
__global__ __launch_bounds__(256, 4) void conv_routing_kernel(
    const float* __restrict__ x,             // [64][32][16][16][16]
    const unsigned short* __restrict__ wTh,  // [288][32][16] f16
    const float* __restrict__ ln1g,
    const float* __restrict__ ln1b,
    const int*   __restrict__ nroute,
    float* __restrict__ vout)                // [64][32][49][16]
{
    __shared__ unsigned short s_inp[288][16];  // f16 x-pairs, 9,216 B
    __shared__ float s_v[32][17];              // 2,176 B
    __shared__ float s_red[2][32][17];         // 4,352 B  => 15,744 B total

    const int tid = threadIdx.x;
    const int m   = tid & 31;
    const int g   = (tid >> 5) & 7;  // 0..7
    const int lw  = tid >> 6;        // 0..3
    const int site = blockIdx.x;
    const int b = site / 49, hw = site % 49;
    const int h = hw / 7, w = hw % 7;

    // stage inp (coalesced float4 loads, f16 pack); row = n*9+kl
    for (int i = tid; i < 1152; i += 256) {    // 288 rows * 4 quads
        const int row = i >> 2, q = i & 3;
        const int n = row / 9, kl = row % 9;
        const int k = kl / 3, l = kl % 3;
        const float4 val = *(const float4*)(
            x + ((((b * 32 + n) * 16 + (2 * h + k)) * 16 + (2 * w + l)) * 16 + q * 4));
        uint2 p;
        p.x = packh2(val.x, val.y);
        p.y = packh2(val.z, val.w);
        *(uint2*)(&s_inp[row][q * 4]) = p;
    }
    __syncthreads();

    const int R = *nroute;
    const int nkl0 = g * 36;
    const unsigned short* const wp0 = wTh + (nkl0 * 32 + m) * 16;

    for (int pass = 0; pass < R; ++pass) {
        float vn[16];
#pragma unroll
        for (int i = 0; i < 16; ++i) vn[i] = 0.f;

        if (pass == 0) {
            const unsigned short* wp = wp0;
            for (int t = 0; t < 36; ++t, wp += 512) {
                const uint4 wa = *(const uint4*)(wp);
                const uint4 wb = *(const uint4*)(wp + 8);
                const unsigned wu[8] = { wa.x, wa.y, wa.z, wa.w, wb.x, wb.y, wb.z, wb.w };
                const uint4* rp = (const uint4*)(&s_inp[nkl0 + t][0]);
                const uint4 ua = rp[0], ub = rp[1];
                const unsigned iu[8] = { ua.x, ua.y, ua.z, ua.w, ub.x, ub.y, ub.z, ub.w };
#pragma unroll
                for (int a = 0; a < 4; ++a) {
#pragma unroll
                    for (int d = 0; d < 4; ++d) {
                        vn[a * 4 + d] = fdot2u(iu[a * 2], wu[d * 2],
                            fdot2u(iu[a * 2 + 1], wu[d * 2 + 1], vn[a * 4 + d]));
                    }
                }
            }
        } else {
            float vrr[16];
#pragma unroll
            for (int i = 0; i < 16; ++i) vrr[i] = s_v[m][i];

            const unsigned short* wp = wp0;
            for (int j = 0; j < 18; ++j, wp += 1024) {   // t-pairs
                const uint4 wa0 = *(const uint4*)(wp);
                const uint4 wb0 = *(const uint4*)(wp + 8);
                const uint4 wa1 = *(const uint4*)(wp + 512);
                const uint4 wb1 = *(const uint4*)(wp + 520);
                const unsigned wu0[8] = { wa0.x, wa0.y, wa0.z, wa0.w, wb0.x, wb0.y, wb0.z, wb0.w };
                const unsigned wu1[8] = { wa1.x, wa1.y, wa1.z, wa1.w, wb1.x, wb1.y, wb1.z, wb1.w };
                const uint4* rp0 = (const uint4*)(&s_inp[nkl0 + 2 * j][0]);
                const uint4* rp1 = (const uint4*)(&s_inp[nkl0 + 2 * j + 1][0]);
                const uint4 ua0 = rp0[0], ub0 = rp0[1];
                const uint4 ua1 = rp1[0], ub1 = rp1[1];
                const unsigned iu0[8] = { ua0.x, ua0.y, ua0.z, ua0.w, ub0.x, ub0.y, ub0.z, ub0.w };
                const unsigned iu1[8] = { ua1.x, ua1.y, ua1.z, ua1.w, ub1.x, ub1.y, ub1.z, ub1.w };

                float uh0[16], uh1[16];
#pragma unroll
                for (int a = 0; a < 4; ++a) {
#pragma unroll
                    for (int d = 0; d < 4; ++d) {
                        uh0[a * 4 + d] = fdot2u(iu0[a * 2], wu0[d * 2],
                            fdot2u(iu0[a * 2 + 1], wu0[d * 2 + 1], 0.f));
                        uh1[a * 4 + d] = fdot2u(iu1[a * 2], wu1[d * 2],
                            fdot2u(iu1[a * 2 + 1], wu1[d * 2 + 1], 0.f));
                    }
                }

                float p0 = 0.f, p1 = 0.f, q0 = 0.f, q1 = 0.f;
#pragma unroll
                for (int i = 0; i < 16; i += 2) {
                    const float c0 = vrr[i], c1 = vrr[i + 1];
                    p0 = fmaf(uh0[i], c0, p0);
                    q0 = fmaf(uh0[i + 1], c1, q0);
                    p1 = fmaf(uh1[i], c0, p1);
                    q1 = fmaf(uh1[i + 1], c1, q1);
                }
                const float e0 = __expf((p0 + q0) * 0.25f);
                const float e1 = __expf((p1 + q1) * 0.25f);

                float sm0 = e0, sm1 = e1;
#pragma unroll
                for (int off = 16; off >= 1; off >>= 1) {
                    const float r0 = __shfl_xor(sm0, off, 32);
                    const float r1 = __shfl_xor(sm1, off, 32);
                    sm0 += r0;
                    sm1 += r1;
                }
                const float qk0 = e0 * __builtin_amdgcn_rcpf(sm0 * (1.f + 1e-10f));
                const float qk1 = e1 * __builtin_amdgcn_rcpf(sm1 * (1.f + 1e-10f));
#pragma unroll
                for (int i = 0; i < 16; ++i) {
                    vn[i] = fmaf(qk0, uh0[i], vn[i]);
                    vn[i] = fmaf(qk1, uh1[i], vn[i]);
                }
            }
        }

#pragma unroll
        for (int i = 0; i < 16; ++i) vn[i] += __shfl_xor(vn[i], 32, 64);

        if (lw >= 2) {
#pragma unroll
            for (int i = 0; i < 16; ++i) s_red[lw - 2][m][i] = vn[i];
        }
        __syncthreads();
        if (lw < 2) {
#pragma unroll
            for (int i = 0; i < 16; ++i) vn[i] += s_red[lw][m][i];
            if (lw == 1) {
#pragma unroll
                for (int i = 0; i < 16; ++i) s_red[1][m][i] = vn[i];
            }
        }
        __syncthreads();
        if (lw == 0) {
#pragma unroll
            for (int i = 0; i < 16; ++i) vn[i] += s_red[1][m][i];
            const float scale = pass ? 1.f : (1.f / 32.f);
            float mu = 0.f;
#pragma unroll
            for (int i = 0; i < 16; ++i) { vn[i] *= scale; mu += vn[i]; }
            mu *= (1.f / 16.f);
            float var = 0.f;
#pragma unroll
            for (int i = 0; i < 16; ++i) {
                const float d0 = vn[i] - mu;
                var = fmaf(d0, d0, var);
            }
            var *= (1.f / 16.f);
            const float inv = rsqrtf(var + LN_EPS);
#pragma unroll
            for (int i = 0; i < 16; ++i)
                s_v[m][i] = (vn[i] - mu) * inv * ln1g[i] + ln1b[i];
        }
        __syncthreads();
    }

    for (int p = tid; p < 512; p += 256) {
        const int mm = p >> 4, i = p & 15;
        vout[((b * 32 + mm) * 49 + hw) * 16 + i] = s_v[mm][i];
    }
}

// ---------------- Stage 2: FC routing ----------------
// fc_pass: 512 blocks = 64 b x 8 chunks; 256 thr = 16 grp x 16 ml.
// For pass>=1, each block redundantly recomputes its b's u from the
// previous pass's partial (combine+LN in LDS) - no ubuf, no extra launch.
__global__ __launch_bounds__(256, 4) void fc_pass(
    const float* __restrict__ fcin,  // [64][1568][16]
    const float* __restrict__ wT2b,  // [1568][16][16] ([n][ml][x*4+d])
    const float* __restrict__ prev,  // [512][16][16] partial from pass-1 (or null)
    const float* __restrict__ ln2g,
    const float* __restrict__ ln2b,
    const int*   __restrict__ nroute,
    const int    pass,
    float* __restrict__ pout)        // [512][16][16]
{
    __shared__ float s_red[4][16][17];
    __shared__ float s_u[16][17];

    const int R = *nroute;
    if (pass >= R) return;
    const int blk = blockIdx.x;
    const int b = blk >> 3, c = blk & 7;
    const int tid = threadIdx.x;
    const int ml = tid & 15, grp = tid >> 4;
    const int wv = tid >> 6;

    float ur[16];
    if (pass) {
        // inline combine + LN: thread (mlf, ii)
        const int mlf = tid >> 4, ii = tid & 15;
        float s = 0.f;
#pragma unroll
        for (int c2 = 0; c2 < 8; ++c2)
            s += prev[((b * 8 + c2) * 16 + mlf) * 16 + ii];
        if (pass == 1) s *= 0.1f;   // pass-0 output carries the 1/Cls scale
        float mu = s;
#pragma unroll
        for (int off = 8; off >= 1; off >>= 1) mu += __shfl_xor(mu, off, 16);
        mu *= (1.f / 16.f);
        const float d0 = s - mu;
        float var = d0 * d0;
#pragma unroll
        for (int off = 8; off >= 1; off >>= 1) var += __shfl_xor(var, off, 16);
        var *= (1.f / 16.f);
        s_u[mlf][ii] = (s - mu) * rsqrtf(var + LN_EPS) * ln2g[ii] + ln2b[ii];
        __syncthreads();
#pragma unroll
        for (int i = 0; i < 16; ++i) ur[i] = s_u[ml][i];
    }

    const float* fb = fcin + (b * 1568 + c * 196) * 16;
    const float* wb = wT2b + (c * 196 * 16) * 16;

    float un[16];
#pragma unroll
    for (int i = 0; i < 16; ++i) un[i] = 0.f;

    for (int t = 0; t < 13; ++t) {
        const int off = t * 16 + grp;
        if (off >= 196) break;
        float iv[16], wv_[16];
        const float* ip = fb + off * 16;
        const float* wp = wb + (off * 16 + ml) * 16;
#pragma unroll
        for (int q = 0; q < 4; ++q) {
            *(float4*)(&iv[q * 4]) = *(const float4*)(ip + q * 4);
            *(float4*)(&wv_[q * 4]) = *(const float4*)(wp + q * 4);
        }
        float vote[16];
#pragma unroll
        for (int a = 0; a < 4; ++a) {
#pragma unroll
            for (int d = 0; d < 4; ++d) {
                float acc = iv[a * 4 + 0] * wv_[0 + d];
                acc = fmaf(iv[a * 4 + 1], wv_[4 + d], acc);
                acc = fmaf(iv[a * 4 + 2], wv_[8 + d], acc);
                acc = fmaf(iv[a * 4 + 3], wv_[12 + d], acc);
                vote[a * 4 + d] = acc;
            }
        }
        if (pass == 0) {
#pragma unroll
            for (int i = 0; i < 16; ++i) un[i] += vote[i];
        } else {
            float l0 = vote[0] * ur[0], l1 = vote[1] * ur[1];
            float l2 = vote[2] * ur[2], l3 = vote[3] * ur[3];
#pragma unroll
            for (int i = 4; i < 16; i += 4) {
                l0 = fmaf(vote[i + 0], ur[i + 0], l0);
                l1 = fmaf(vote[i + 1], ur[i + 1], l1);
                l2 = fmaf(vote[i + 2], ur[i + 2], l2);
                l3 = fmaf(vote[i + 3], ur[i + 3], l3);
            }
            const float lg = ((l0 + l1) + (l2 + l3)) * 0.25f;
            float e = __expf(lg);
            if (ml >= 10) e = 0.f;
            float sm = e;
#pragma unroll
            for (int off2 = 8; off2 >= 1; off2 >>= 1)
                sm += __shfl_xor(sm, off2, 16);
            const float qk = e * __builtin_amdgcn_rcpf(sm * (1.f + 1e-10f));
#pragma unroll
            for (int i = 0; i < 16; ++i) un[i] = fmaf(qk, vote[i], un[i]);
        }
    }

#pragma unroll
    for (int i = 0; i < 16; ++i) {
        un[i] += __shfl_xor(un[i], 16, 64);
        un[i] += __shfl_xor(un[i], 32, 64);
    }
    if ((tid & 63) < 16) {
#pragma unroll
        for (int i = 0; i < 16; ++i) s_red[wv][ml][i] = un[i];
    }
    __syncthreads();
    {
        const int mlf = tid >> 4, i = tid & 15;
        const float s = s_red[0][mlf][i] + s_red[1][mlf][i]
                      + s_red[2][mlf][i] + s_red[3][mlf][i];
        pout[(blk * 16 + mlf) * 16 + i] = s;
    }
}

// fc_final: combine the last pass's partial, LN, write out.
__global__ __launch_bounds__(256) void fc_final(
    const float* __restrict__ pA,    // partial written by even passes
    const float* __restrict__ pB,    // partial written by odd passes
    const float* __restrict__ ln2g,
    const float* __restrict__ ln2b,
    const int*   __restrict__ nroute,
    float* __restrict__ out)         // [64][10][16]
{
    const int R = *nroute;
    const float* P = ((R - 1) & 1) ? pB : pA;
    const int b = blockIdx.x;
    const int tid = threadIdx.x;
    const int i = tid & 15, ml = tid >> 4;

    float s = 0.f;
#pragma unroll
    for (int c = 0; c < 8; ++c)
        s += P[((b * 8 + c) * 16 + ml) * 16 + i];
    if (R == 1) s *= 0.1f;

    float mu = s;
#pragma unroll
    for (int off = 8; off >= 1; off >>= 1) mu += __shfl_xor(mu, off, 16);
    mu *= (1.f / 16.f);
    const float d0 = s - mu;
    float var = d0 * d0;
#pragma unroll
    for (int off = 8; off >= 1; off >>= 1) var += __shfl_xor(var, off, 16);
    var *= (1.f / 16.f);
    const float r = (s - mu) * rsqrtf(var + LN_EPS) * ln2g[i] + ln2b[i];

    if (ml < 10) out[(b * 10 + ml) * 16 + i] = r;
}

// ---------------- fallback 6-launch fc kernels (proven R14 path) ----------------
__global__ __launch_bounds__(256, 4) void fc_partial(
    const float* __restrict__ fcin, const float* __restrict__ wT2b,
    const float* __restrict__ u, const int* __restrict__ nroute,
    const int pass, float* __restrict__ partial)
{
    __shared__ float s_red[4][16][17];
    const int R = *nroute;
    if (pass >= R) return;
    const int blk = blockIdx.x;
    const int b = blk >> 3, c = blk & 7;
    const int tid = threadIdx.x;
    const int ml = tid & 15, grp = tid >> 4;
    const int wv = tid >> 6;
    const float* fb = fcin + (b * 1568 + c * 196) * 16;
    const float* wb = wT2b + (c * 196 * 16) * 16;

    float un[16];
#pragma unroll
    for (int i = 0; i < 16; ++i) un[i] = 0.f;
    float ur[16];
    if (pass) {
#pragma unroll
        for (int q = 0; q < 4; ++q)
            *(float4*)(&ur[q * 4]) = *(const float4*)(u + (b * 16 + ml) * 16 + q * 4);
    }
    for (int t = 0; t < 13; ++t) {
        const int off = t * 16 + grp;
        if (off >= 196) break;
        float iv[16], wv_[16];
        const float* ip = fb + off * 16;
        const float* wp = wb + (off * 16 + ml) * 16;
#pragma unroll
        for (int q = 0; q < 4; ++q) {
            *(float4*)(&iv[q * 4]) = *(const float4*)(ip + q * 4);
            *(float4*)(&wv_[q * 4]) = *(const float4*)(wp + q * 4);
        }
        float vote[16];
#pragma unroll
        for (int a = 0; a < 4; ++a) {
#pragma unroll
            for (int d = 0; d < 4; ++d) {
                float acc = iv[a * 4 + 0] * wv_[0 + d];
                acc = fmaf(iv[a * 4 + 1], wv_[4 + d], acc);
                acc = fmaf(iv[a * 4 + 2], wv_[8 + d], acc);
                acc = fmaf(iv[a * 4 + 3], wv_[12 + d], acc);
                vote[a * 4 + d] = acc;
            }
        }
        if (pass == 0) {
#pragma unroll
            for (int i = 0; i < 16; ++i) un[i] += vote[i];
        } else {
            float l0 = vote[0] * ur[0], l1 = vote[1] * ur[1];
            float l2 = vote[2] * ur[2], l3 = vote[3] * ur[3];
#pragma unroll
            for (int i = 4; i < 16; i += 4) {
                l0 = fmaf(vote[i + 0], ur[i + 0], l0);
                l1 = fmaf(vote[i + 1], ur[i + 1], l1);
                l2 = fmaf(vote[i + 2], ur[i + 2], l2);
                l3 = fmaf(vote[i + 3], ur[i + 3], l3);
            }
            const float lg = ((l0 + l1) + (l2 + l3)) * 0.25f;
            float e = __expf(lg);
            if (ml >= 10) e = 0.f;
            float sm = e;
#pragma unroll
            for (int off2 = 8; off2 >= 1; off2 >>= 1)
                sm += __shfl_xor(sm, off2, 16);
            const float qk = e * __builtin_amdgcn_rcpf(sm * (1.f + 1e-10f));
#pragma unroll
            for (int i = 0; i < 16; ++i) un[i] = fmaf(qk, vote[i], un[i]);
        }
    }
#pragma unroll
    for (int i = 0; i < 16; ++i) {
        un[i] += __shfl_xor(un[i], 16, 64);
        un[i] += __shfl_xor(un[i], 32, 64);
    }
    if ((tid & 63) < 16) {
#pragma unroll
        for (int i = 0; i < 16; ++i) s_red[wv][ml][i] = un[i];
    }
    __syncthreads();
    {
        const int mlf = tid >> 4, i = tid & 15;
        const float s = s_red[0][mlf][i] + s_red[1][mlf][i]
                      + s_red[2][mlf][i] + s_red[3][mlf][i];
        partial[(blk * 16 + mlf) * 16 + i] = s;
    }
}

__global__ __launch_bounds__(256) void fc_combine(
    const float* __restrict__ partial, const float* __restrict__ ln2g,
    const float* __restrict__ ln2b, const int* __restrict__ nroute,
    const int pass, float* __restrict__ u, float* __restrict__ out)
{
    const int R = *nroute;
    if (pass >= R) return;
    const int b = blockIdx.x;
    const int tid = threadIdx.x;
    const int i = tid & 15, ml = tid >> 4;
    float s = 0.f;
#pragma unroll
    for (int c = 0; c < 8; ++c)
        s += partial[((b * 8 + c) * 16 + ml) * 16 + i];
    if (pass == 0) s *= 0.1f;
    float mu = s;
#pragma unroll
    for (int off = 8; off >= 1; off >>= 1) mu += __shfl_xor(mu, off, 16);
    mu *= (1.f / 16.f);
    const float d0 = s - mu;
    float var = d0 * d0;
#pragma unroll
    for (int off = 8; off >= 1; off >>= 1) var += __shfl_xor(var, off, 16);
    var *= (1.f / 16.f);
    const float r = (s - mu) * rsqrtf(var + LN_EPS) * ln2g[i] + ln2b[i];
    u[(b * 16 + ml) * 16 + i] = r;
    if (pass == R - 1 && ml < 10) out[(b * 10 + ml) * 16 + i] = r;
}

extern "C" void kernel_launch(void* const* d_in, const int* in_sizes, int n_in,
                              void* d_out, int out_size, void* d_ws, size_t ws_size,
                              hipStream_t stream) {
    const float* x     = (const float*)d_in[0];
    const float* wconv = (const float*)d_in[1];
    const float* wfc   = (const float*)d_in[2];
    const float* ln1g  = (const float*)d_in[3];
    const float* ln1b  = (const float*)d_in[4];
    const float* ln2g  = (const float*)d_in[5];
    const float* ln2b  = (const float*)d_in[6];
    const int*   nrt   = (const int*)d_in[7];
    float* out = (float*)d_out;

    float* vout = (float*)d_ws;                                  // 6,422,528 B

    if (ws_size >= 9076736) {
        // new layout: wT2b | pA (wTh aliases its head; dead after conv) | pB
        float* wT2b = (float*)((char*)d_ws + 6422528);           // 1,605,632 B
        float* pA   = (float*)((char*)d_ws + 8028160);           // 524,288 B
        float* pB   = (float*)((char*)d_ws + 8552448);           // 524,288 B
        unsigned short* wTh = (unsigned short*)pA;               // 294,912 B alias

        hipLaunchKernelGGL(transpose_weights, dim3(2144), dim3(256), 0, stream,
                           wconv, wfc, wTh, wT2b);
        hipLaunchKernelGGL(conv_routing_kernel, dim3(3136), dim3(256), 0, stream,
                           x, wTh, ln1g, ln1b, nrt, vout);
        hipLaunchKernelGGL(fc_pass, dim3(512), dim3(256), 0, stream,
                           vout, wT2b, (const float*)nullptr, ln2g, ln2b, nrt, 0, pA);
        hipLaunchKernelGGL(fc_pass, dim3(512), dim3(256), 0, stream,
                           vout, wT2b, (const float*)pA, ln2g, ln2b, nrt, 1, pB);
        hipLaunchKernelGGL(fc_pass, dim3(512), dim3(256), 0, stream,
                           vout, wT2b, (const float*)pB, ln2g, ln2b, nrt, 2, pA);
        hipLaunchKernelGGL(fc_final, dim3(64), dim3(256), 0, stream,
                           pA, pB, ln2g, ln2b, nrt, out);
    } else {
        // fallback: R14's proven tight layout, 6-launch fc
        unsigned short* wTh = (unsigned short*)((char*)d_ws + 6422528);
        float* wT2b    = (float*)((char*)d_ws + 6422528);        // aliases wTh
        float* ubuf    = (float*)((char*)d_ws + 8028160);        // 65,536 B
        float* partial = (float*)((char*)d_ws + 8093696);        // 524,288 B

        hipLaunchKernelGGL(transpose_wconv, dim3(576), dim3(256), 0, stream,
                           wconv, wTh);
        hipLaunchKernelGGL(conv_routing_kernel, dim3(3136), dim3(256), 0, stream,
                           x, wTh, ln1g, ln1b, nrt, vout);
        hipLaunchKernelGGL(transpose_wfc, dim3(1568), dim3(256), 0, stream,
                           wfc, wT2b);
        for (int pass = 0; pass < 3; ++pass) {
            hipLaunchKernelGGL(fc_partial, dim3(512), dim3(256), 0, stream,
                               vout, wT2b, ubuf, nrt, pass, partial);
            hipLaunchKernelGGL(fc_combine, dim3(64), dim3(256), 0, stream,
                               partial, ln2g, ln2b, nrt, pass, ubuf, out);
        }
    }
}

// Round 6
// 292.731 us; speedup vs baseline: 3.8001x; 1.0640x over previous
//
#include <hip/hip_runtime.h>
#include <hip/hip_bf16.h>

// CapsModel: B=64 N=32 H=W=16 A=16 K=3 stride=2 -> Ho=Wo=7, M=32, SD=4, D=16
// R22: R21 structure, ONE mechanism changed: cross-lane softmax reductions
//   in the HOT loops now use DPP adds instead of __shfl_xor (DS-based).
//   Evidence: R21 cut VALU instr (~5% VALUBusy drop) with FLAT duration =>
//   kernel is latency-bound, not VALU-issue-bound. The 5-level shfl butterfly
//   is ~200-300 serial cycles/j (5 LDS round-trips + lgkmcnt waits).
//   conv: 4 DPP levels (xor1,xor2,ror4,ror8 -> 16-lane sum) + 1 ds_swizzle
//   xor16 (0x401F) for the 32-lane half-wave sum. DS ops/j: 10 -> 2.
//   fc_pass: width-16 softmax -> pure DPP (zero DS).
//   Prediction: conv 216 -> 180-200us. Flat => butterfly off critical path
//   -> next: unroll-2 under (256,3). Spill tell: WRITE_SIZE == 6.27MB.
// conv structure: one site per block, 3136 x 256 thr, t-PAIRS, (256,4),
//   VGPR 52. MFMA rewrites R18/R19 lost to this -- no revisit w/o disasm.
// fc routing R16: 4 launches, prev-partial double-buffered.

#define LN_EPS 1e-5f

typedef _Float16 h2 __attribute__((ext_vector_type(2)));

__device__ __forceinline__ unsigned packh2(float a, float b) {
    const unsigned short ua = __builtin_bit_cast(unsigned short, (_Float16)a);
    const unsigned short ub = __builtin_bit_cast(unsigned short, (_Float16)b);
    return (unsigned)ua | ((unsigned)ub << 16);
}

// force v_dot2_f32_f16 (f32 += a.lo*b.lo + a.hi*b.hi, f16 inputs). (R21)
__device__ __forceinline__ float fdot2u(unsigned a, unsigned b, float c) {
    float d;
    asm("v_dot2_f32_f16 %0, %1, %2, %3" : "=v"(d) : "v"(a), "v"(b), "v"(c));
    return d;
}

// R22: DPP cross-lane add helpers (no LDS). ctrl: 0xB1=quad_perm[1,0,3,2]
// (xor1), 0x4E=quad_perm[2,3,0,1] (xor2), 0x124=row_ror:4, 0x128=row_ror:8.
template <int CTRL>
__device__ __forceinline__ float dpp_add(float x) {
    return x + __builtin_bit_cast(float,
        __builtin_amdgcn_mov_dpp(__builtin_bit_cast(int, x), CTRL, 0xF, 0xF, false));
}
// 16-lane (DPP row) all-lanes sum.
__device__ __forceinline__ float row16_sum(float x) {
    x = dpp_add<0xB1>(x);
    x = dpp_add<0x4E>(x);
    x = dpp_add<0x124>(x);
    x = dpp_add<0x128>(x);
    return x;
}
// cross-row xor16 within each 32-lane half (BitMode swizzle 0x401F).
__device__ __forceinline__ float swz_xor16(float x) {
    return __builtin_bit_cast(float,
        __builtin_amdgcn_ds_swizzle(__builtin_bit_cast(int, x), 0x401F));
}

// ---------------- weight transposes ----------------
// wTh [288][32][16] f16: row r = n*9+kl; inner idx = d*4+x (x-pairs adjacent).
__global__ __launch_bounds__(256) void transpose_wconv(
    const float* __restrict__ wconv, unsigned short* __restrict__ wTh)
{
    const int i = blockIdx.x * 256 + threadIdx.x;
    if (i < 147456) {
        const int x = i & 3, d = (i >> 2) & 3, mm = (i >> 4) & 31, r = i >> 9;
        const int n = r / 9, kl = r % 9;
        const float v = wconv[((kl * 32 + n) * 16 + x * 4 + d) * 32 + mm];
        wTh[i] = __builtin_bit_cast(unsigned short, (_Float16)v);
    }
}
// wT2b [1568][16][16] fp32: [n][m (pad 10->16, zeros)][x*4+d]
__global__ __launch_bounds__(256) void transpose_wfc(
    const float* __restrict__ wfc, float* __restrict__ wT2b)
{
    const int j = blockIdx.x * 256 + threadIdx.x;
    if (j < 401408) {
        const int xd = j & 15, mm = (j >> 4) & 15, n = j >> 8;
        const int x = xd >> 2, dd = xd & 3;
        wT2b[j] = (mm < 10) ? wfc[((n * 4 + x) * 4 + dd) * 10 + mm] : 0.f;
    }
}
// fused (roomy ws layout)
__global__ __launch_bounds__(256) void transpose_weights(
    const float* __restrict__ wconv, const float* __restrict__ wfc,
    unsigned short* __restrict__ wTh, float* __restrict__ wT2b)
{
    const int blk = blockIdx.x;
    if (blk < 576) {
        const int i = blk * 256 + threadIdx.x;
        if (i < 147456) {
            const int x = i & 3, d = (i >> 2) & 3, mm = (i >> 4) & 31, r = i >> 9;
            const int n = r / 9, kl = r % 9;
            const float v = wconv[((kl * 32 + n) * 16 + x * 4 + d) * 32 + mm];
            wTh[i] = __builtin_bit_cast(unsigned short, (_Float16)v);
        }
    } else {
        const int j = (blk - 576) * 256 + threadIdx.x;
        if (j < 401408) {
            const int xd = j & 15, mm = (j >> 4) & 15, n = j >> 8;
            const int x = xd >> 2, dd = xd & 3;
            wT2b[j] = (mm < 10) ? wfc[((n * 4 + x) * 4 + dd) * 10 + mm] : 0.f;
        }
    }
}

// ---------------- Stage 1: conv routing ----------------
__global__ __launch_bounds__(256, 4) void conv_routing_kernel(
    const float* __restrict__ x,             // [64][32][16][16][16]
    const unsigned short* __restrict__ wTh,  // [288][32][16] f16
    const float* __restrict__ ln1g,
    const float* __restrict__ ln1b,
    const int*   __restrict__ nroute,
    float* __restrict__ vout)                // [64][32][49][16]
{
    __shared__ unsigned short s_inp[288][16];  // f16 x-pairs, 9,216 B
    __shared__ float s_v[32][17];              // 2,176 B
    __shared__ float s_red[2][32][17];         // 4,352 B  => 15,744 B total

    const int tid = threadIdx.x;
    const int m   = tid & 31;
    const int g   = (tid >> 5) & 7;  // 0..7
    const int lw  = tid >> 6;        // 0..3
    const int site = blockIdx.x;
    const int b = site / 49, hw = site % 49;
    const int h = hw / 7, w = hw % 7;

    // stage inp (coalesced float4 loads, f16 pack); row = n*9+kl
    for (int i = tid; i < 1152; i += 256) {    // 288 rows * 4 quads
        const int row = i >> 2, q = i & 3;
        const int n = row / 9, kl = row % 9;
        const int k = kl / 3, l = kl % 3;
        const float4 val = *(const float4*)(
            x + ((((b * 32 + n) * 16 + (2 * h + k)) * 16 + (2 * w + l)) * 16 + q * 4));
        uint2 p;
        p.x = packh2(val.x, val.y);
        p.y = packh2(val.z, val.w);
        *(uint2*)(&s_inp[row][q * 4]) = p;
    }
    __syncthreads();

    const int R = *nroute;
    const int nkl0 = g * 36;
    const unsigned short* const wp0 = wTh + (nkl0 * 32 + m) * 16;

    for (int pass = 0; pass < R; ++pass) {
        float vn[16];
#pragma unroll
        for (int i = 0; i < 16; ++i) vn[i] = 0.f;

        if (pass == 0) {
            const unsigned short* wp = wp0;
            for (int t = 0; t < 36; ++t, wp += 512) {
                const uint4 wa = *(const uint4*)(wp);
                const uint4 wb = *(const uint4*)(wp + 8);
                const unsigned wu[8] = { wa.x, wa.y, wa.z, wa.w, wb.x, wb.y, wb.z, wb.w };
                const uint4* rp = (const uint4*)(&s_inp[nkl0 + t][0]);
                const uint4 ua = rp[0], ub = rp[1];
                const unsigned iu[8] = { ua.x, ua.y, ua.z, ua.w, ub.x, ub.y, ub.z, ub.w };
#pragma unroll
                for (int a = 0; a < 4; ++a) {
#pragma unroll
                    for (int d = 0; d < 4; ++d) {
                        vn[a * 4 + d] = fdot2u(iu[a * 2], wu[d * 2],
                            fdot2u(iu[a * 2 + 1], wu[d * 2 + 1], vn[a * 4 + d]));
                    }
                }
            }
        } else {
            float vrr[16];
#pragma unroll
            for (int i = 0; i < 16; ++i) vrr[i] = s_v[m][i];

            const unsigned short* wp = wp0;
            for (int j = 0; j < 18; ++j, wp += 1024) {   // t-pairs
                const uint4 wa0 = *(const uint4*)(wp);
                const uint4 wb0 = *(const uint4*)(wp + 8);
                const uint4 wa1 = *(const uint4*)(wp + 512);
                const uint4 wb1 = *(const uint4*)(wp + 520);
                const unsigned wu0[8] = { wa0.x, wa0.y, wa0.z, wa0.w, wb0.x, wb0.y, wb0.z, wb0.w };
                const unsigned wu1[8] = { wa1.x, wa1.y, wa1.z, wa1.w, wb1.x, wb1.y, wb1.z, wb1.w };
                const uint4* rp0 = (const uint4*)(&s_inp[nkl0 + 2 * j][0]);
                const uint4* rp1 = (const uint4*)(&s_inp[nkl0 + 2 * j + 1][0]);
                const uint4 ua0 = rp0[0], ub0 = rp0[1];
                const uint4 ua1 = rp1[0], ub1 = rp1[1];
                const unsigned iu0[8] = { ua0.x, ua0.y, ua0.z, ua0.w, ub0.x, ub0.y, ub0.z, ub0.w };
                const unsigned iu1[8] = { ua1.x, ua1.y, ua1.z, ua1.w, ub1.x, ub1.y, ub1.z, ub1.w };

                float uh0[16], uh1[16];
#pragma unroll
                for (int a = 0; a < 4; ++a) {
#pragma unroll
                    for (int d = 0; d < 4; ++d) {
                        uh0[a * 4 + d] = fdot2u(iu0[a * 2], wu0[d * 2],
                            fdot2u(iu0[a * 2 + 1], wu0[d * 2 + 1], 0.f));
                        uh1[a * 4 + d] = fdot2u(iu1[a * 2], wu1[d * 2],
                            fdot2u(iu1[a * 2 + 1], wu1[d * 2 + 1], 0.f));
                    }
                }

                float p0 = 0.f, p1 = 0.f, q0 = 0.f, q1 = 0.f;
#pragma unroll
                for (int i = 0; i < 16; i += 2) {
                    const float c0 = vrr[i], c1 = vrr[i + 1];
                    p0 = fmaf(uh0[i], c0, p0);
                    q0 = fmaf(uh0[i + 1], c1, q0);
                    p1 = fmaf(uh1[i], c0, p1);
                    q1 = fmaf(uh1[i + 1], c1, q1);
                }
                const float e0 = __expf((p0 + q0) * 0.25f);
                const float e1 = __expf((p1 + q1) * 0.25f);

                // R22: DPP 16-lane sum + one xor16 swizzle -> 32-lane sum
                // (was 5 DS-shuffle round-trips per value).
                float sm0 = row16_sum(e0);
                float sm1 = row16_sum(e1);
                sm0 += swz_xor16(sm0);
                sm1 += swz_xor16(sm1);

                const float qk0 = e0 * __builtin_amdgcn_rcpf(sm0 * (1.f + 1e-10f));
                const float qk1 = e1 * __builtin_amdgcn_rcpf(sm1 * (1.f + 1e-10f));
#pragma unroll
                for (int i = 0; i < 16; ++i) {
                    vn[i] = fmaf(qk0, uh0[i], vn[i]);
                    vn[i] = fmaf(qk1, uh1[i], vn[i]);
                }
            }
        }

#pragma unroll
        for (int i = 0; i < 16; ++i) vn[i] += __shfl_xor(vn[i], 32, 64);

        if (lw >= 2) {
#pragma unroll
            for (int i = 0; i < 16; ++i) s_red[lw - 2][m][i] = vn[i];
        }
        __syncthreads();
        if (lw < 2) {
#pragma unroll
            for (int i = 0; i < 16; ++i) vn[i] += s_red[lw][m][i];
            if (lw == 1) {
#pragma unroll
                for (int i = 0; i < 16; ++i) s_red[1][m][i] = vn[i];
            }
        }
        __syncthreads();
        if (lw == 0) {
#pragma unroll
            for (int i = 0; i < 16; ++i) vn[i] += s_red[1][m][i];
            const float scale = pass ? 1.f : (1.f / 32.f);
            float mu = 0.f;
#pragma unroll
            for (int i = 0; i < 16; ++i) { vn[i] *= scale; mu += vn[i]; }
            mu *= (1.f / 16.f);
            float var = 0.f;
#pragma unroll
            for (int i = 0; i < 16; ++i) {
                const float d0 = vn[i] - mu;
                var = fmaf(d0, d0, var);
            }
            var *= (1.f / 16.f);
            const float inv = rsqrtf(var + LN_EPS);
#pragma unroll
            for (int i = 0; i < 16; ++i)
                s_v[m][i] = (vn[i] - mu) * inv * ln1g[i] + ln1b[i];
        }
        __syncthreads();
    }

    for (int p = tid; p < 512; p += 256) {
        const int mm = p >> 4, i = p & 15;
        vout[((b * 32 + mm) * 49 + hw) * 16 + i] = s_v[mm][i];
    }
}

// ---------------- Stage 2: FC routing ----------------
// fc_pass: 512 blocks = 64 b x 8 chunks; 256 thr = 16 grp x 16 ml.
// For pass>=1, each block redundantly recomputes its b's u from the
// previous pass's partial (combine+LN in LDS) - no ubuf, no extra launch.
__global__ __launch_bounds__(256, 4) void fc_pass(
    const float* __restrict__ fcin,  // [64][1568][16]
    const float* __restrict__ wT2b,  // [1568][16][16] ([n][ml][x*4+d])
    const float* __restrict__ prev,  // [512][16][16] partial from pass-1 (or null)
    const float* __restrict__ ln2g,
    const float* __restrict__ ln2b,
    const int*   __restrict__ nroute,
    const int    pass,
    float* __restrict__ pout)        // [512][16][16]
{
    __shared__ float s_red[4][16][17];
    __shared__ float s_u[16][17];

    const int R = *nroute;
    if (pass >= R) return;
    const int blk = blockIdx.x;
    const int b = blk >> 3, c = blk & 7;
    const int tid = threadIdx.x;
    const int ml = tid & 15, grp = tid >> 4;
    const int wv = tid >> 6;

    float ur[16];
    if (pass) {
        // inline combine + LN: thread (mlf, ii)
        const int mlf = tid >> 4, ii = tid & 15;
        float s = 0.f;
#pragma unroll
        for (int c2 = 0; c2 < 8; ++c2)
            s += prev[((b * 8 + c2) * 16 + mlf) * 16 + ii];
        if (pass == 1) s *= 0.1f;   // pass-0 output carries the 1/Cls scale
        float mu = s;
#pragma unroll
        for (int off = 8; off >= 1; off >>= 1) mu += __shfl_xor(mu, off, 16);
        mu *= (1.f / 16.f);
        const float d0 = s - mu;
        float var = d0 * d0;
#pragma unroll
        for (int off = 8; off >= 1; off >>= 1) var += __shfl_xor(var, off, 16);
        var *= (1.f / 16.f);
        s_u[mlf][ii] = (s - mu) * rsqrtf(var + LN_EPS) * ln2g[ii] + ln2b[ii];
        __syncthreads();
#pragma unroll
        for (int i = 0; i < 16; ++i) ur[i] = s_u[ml][i];
    }

    const float* fb = fcin + (b * 1568 + c * 196) * 16;
    const float* wb = wT2b + (c * 196 * 16) * 16;

    float un[16];
#pragma unroll
    for (int i = 0; i < 16; ++i) un[i] = 0.f;

    for (int t = 0; t < 13; ++t) {
        const int off = t * 16 + grp;
        if (off >= 196) break;
        float iv[16], wv_[16];
        const float* ip = fb + off * 16;
        const float* wp = wb + (off * 16 + ml) * 16;
#pragma unroll
        for (int q = 0; q < 4; ++q) {
            *(float4*)(&iv[q * 4]) = *(const float4*)(ip + q * 4);
            *(float4*)(&wv_[q * 4]) = *(const float4*)(wp + q * 4);
        }
        float vote[16];
#pragma unroll
        for (int a = 0; a < 4; ++a) {
#pragma unroll
            for (int d = 0; d < 4; ++d) {
                float acc = iv[a * 4 + 0] * wv_[0 + d];
                acc = fmaf(iv[a * 4 + 1], wv_[4 + d], acc);
                acc = fmaf(iv[a * 4 + 2], wv_[8 + d], acc);
                acc = fmaf(iv[a * 4 + 3], wv_[12 + d], acc);
                vote[a * 4 + d] = acc;
            }
        }
        if (pass == 0) {
#pragma unroll
            for (int i = 0; i < 16; ++i) un[i] += vote[i];
        } else {
            float l0 = vote[0] * ur[0], l1 = vote[1] * ur[1];
            float l2 = vote[2] * ur[2], l3 = vote[3] * ur[3];
#pragma unroll
            for (int i = 4; i < 16; i += 4) {
                l0 = fmaf(vote[i + 0], ur[i + 0], l0);
                l1 = fmaf(vote[i + 1], ur[i + 1], l1);
                l2 = fmaf(vote[i + 2], ur[i + 2], l2);
                l3 = fmaf(vote[i + 3], ur[i + 3], l3);
            }
            const float lg = ((l0 + l1) + (l2 + l3)) * 0.25f;
            float e = __expf(lg);
            if (ml >= 10) e = 0.f;
            // R22: width-16 softmax sum via pure DPP (zero DS round-trips).
            const float sm = row16_sum(e);
            const float qk = e * __builtin_amdgcn_rcpf(sm * (1.f + 1e-10f));
#pragma unroll
            for (int i = 0; i < 16; ++i) un[i] = fmaf(qk, vote[i], un[i]);
        }
    }

#pragma unroll
    for (int i = 0; i < 16; ++i) {
        un[i] += __shfl_xor(un[i], 16, 64);
        un[i] += __shfl_xor(un[i], 32, 64);
    }
    if ((tid & 63) < 16) {
#pragma unroll
        for (int i = 0; i < 16; ++i) s_red[wv][ml][i] = un[i];
    }
    __syncthreads();
    {
        const int mlf = tid >> 4, i = tid & 15;
        const float s = s_red[0][mlf][i] + s_red[1][mlf][i]
                      + s_red[2][mlf][i] + s_red[3][mlf][i];
        pout[(blk * 16 + mlf) * 16 + i] = s;
    }
}

// fc_final: combine the last pass's partial, LN, write out.
__global__ __launch_bounds__(256) void fc_final(
    const float* __restrict__ pA,    // partial written by even passes
    const float* __restrict__ pB,    // partial written by odd passes
    const float* __restrict__ ln2g,
    const float* __restrict__ ln2b,
    const int*   __restrict__ nroute,
    float* __restrict__ out)         // [64][10][16]
{
    const int R = *nroute;
    const float* P = ((R - 1) & 1) ? pB : pA;
    const int b = blockIdx.x;
    const int tid = threadIdx.x;
    const int i = tid & 15, ml = tid >> 4;

    float s = 0.f;
#pragma unroll
    for (int c = 0; c < 8; ++c)
        s += P[((b * 8 + c) * 16 + ml) * 16 + i];
    if (R == 1) s *= 0.1f;

    float mu = s;
#pragma unroll
    for (int off = 8; off >= 1; off >>= 1) mu += __shfl_xor(mu, off, 16);
    mu *= (1.f / 16.f);
    const float d0 = s - mu;
    float var = d0 * d0;
#pragma unroll
    for (int off = 8; off >= 1; off >>= 1) var += __shfl_xor(var, off, 16);
    var *= (1.f / 16.f);
    const float r = (s - mu) * rsqrtf(var + LN_EPS) * ln2g[i] + ln2b[i];

    if (ml < 10) out[(b * 10 + ml) * 16 + i] = r;
}

// ---------------- fallback 6-launch fc kernels (proven R14 path) ----------------
__global__ __launch_bounds__(256, 4) void fc_partial(
    const float* __restrict__ fcin, const float* __restrict__ wT2b,
    const float* __restrict__ u, const int* __restrict__ nroute,
    const int pass, float* __restrict__ partial)
{
    __shared__ float s_red[4][16][17];
    const int R = *nroute;
    if (pass >= R) return;
    const int blk = blockIdx.x;
    const int b = blk >> 3, c = blk & 7;
    const int tid = threadIdx.x;
    const int ml = tid & 15, grp = tid >> 4;
    const int wv = tid >> 6;
    const float* fb = fcin + (b * 1568 + c * 196) * 16;
    const float* wb = wT2b + (c * 196 * 16) * 16;

    float un[16];
#pragma unroll
    for (int i = 0; i < 16; ++i) un[i] = 0.f;
    float ur[16];
    if (pass) {
#pragma unroll
        for (int q = 0; q < 4; ++q)
            *(float4*)(&ur[q * 4]) = *(const float4*)(u + (b * 16 + ml) * 16 + q * 4);
    }
    for (int t = 0; t < 13; ++t) {
        const int off = t * 16 + grp;
        if (off >= 196) break;
        float iv[16], wv_[16];
        const float* ip = fb + off * 16;
        const float* wp = wb + (off * 16 + ml) * 16;
#pragma unroll
        for (int q = 0; q < 4; ++q) {
            *(float4*)(&iv[q * 4]) = *(const float4*)(ip + q * 4);
            *(float4*)(&wv_[q * 4]) = *(const float4*)(wp + q * 4);
        }
        float vote[16];
#pragma unroll
        for (int a = 0; a < 4; ++a) {
#pragma unroll
            for (int d = 0; d < 4; ++d) {
                float acc = iv[a * 4 + 0] * wv_[0 + d];
                acc = fmaf(iv[a * 4 + 1], wv_[4 + d], acc);
                acc = fmaf(iv[a * 4 + 2], wv_[8 + d], acc);
                acc = fmaf(iv[a * 4 + 3], wv_[12 + d], acc);
                vote[a * 4 + d] = acc;
            }
        }
        if (pass == 0) {
#pragma unroll
            for (int i = 0; i < 16; ++i) un[i] += vote[i];
        } else {
            float l0 = vote[0] * ur[0], l1 = vote[1] * ur[1];
            float l2 = vote[2] * ur[2], l3 = vote[3] * ur[3];
#pragma unroll
            for (int i = 4; i < 16; i += 4) {
                l0 = fmaf(vote[i + 0], ur[i + 0], l0);
                l1 = fmaf(vote[i + 1], ur[i + 1], l1);
                l2 = fmaf(vote[i + 2], ur[i + 2], l2);
                l3 = fmaf(vote[i + 3], ur[i + 3], l3);
            }
            const float lg = ((l0 + l1) + (l2 + l3)) * 0.25f;
            float e = __expf(lg);
            if (ml >= 10) e = 0.f;
            float sm = e;
#pragma unroll
            for (int off2 = 8; off2 >= 1; off2 >>= 1)
                sm += __shfl_xor(sm, off2, 16);
            const float qk = e * __builtin_amdgcn_rcpf(sm * (1.f + 1e-10f));
#pragma unroll
            for (int i = 0; i < 16; ++i) un[i] = fmaf(qk, vote[i], un[i]);
        }
    }
#pragma unroll
    for (int i = 0; i < 16; ++i) {
        un[i] += __shfl_xor(un[i], 16, 64);
        un[i] += __shfl_xor(un[i], 32, 64);
    }
    if ((tid & 63) < 16) {
#pragma unroll
        for (int i = 0; i < 16; ++i) s_red[wv][ml][i] = un[i];
    }
    __syncthreads();
    {
        const int mlf = tid >> 4, i = tid & 15;
        const float s = s_red[0][mlf][i] + s_red[1][mlf][i]
                      + s_red[2][mlf][i] + s_red[3][mlf][i];
        partial[(blk * 16 + mlf) * 16 + i] = s;
    }
}

__global__ __launch_bounds__(256) void fc_combine(
    const float* __restrict__ partial, const float* __restrict__ ln2g,
    const float* __restrict__ ln2b, const int* __restrict__ nroute,
    const int pass, float* __restrict__ u, float* __restrict__ out)
{
    const int R = *nroute;
    if (pass >= R) return;
    const int b = blockIdx.x;
    const int tid = threadIdx.x;
    const int i = tid & 15, ml = tid >> 4;
    float s = 0.f;
#pragma unroll
    for (int c = 0; c < 8; ++c)
        s += partial[((b * 8 + c) * 16 + ml) * 16 + i];
    if (pass == 0) s *= 0.1f;
    float mu = s;
#pragma unroll
    for (int off = 8; off >= 1; off >>= 1) mu += __shfl_xor(mu, off, 16);
    mu *= (1.f / 16.f);
    const float d0 = s - mu;
    float var = d0 * d0;
#pragma unroll
    for (int off = 8; off >= 1; off >>= 1) var += __shfl_xor(var, off, 16);
    var *= (1.f / 16.f);
    const float r = (s - mu) * rsqrtf(var + LN_EPS) * ln2g[i] + ln2b[i];
    u[(b * 16 + ml) * 16 + i] = r;
    if (pass == R - 1 && ml < 10) out[(b * 10 + ml) * 16 + i] = r;
}

extern "C" void kernel_launch(void* const* d_in, const int* in_sizes, int n_in,
                              void* d_out, int out_size, void* d_ws, size_t ws_size,
                              hipStream_t stream) {
    const float* x     = (const float*)d_in[0];
    const float* wconv = (const float*)d_in[1];
    const float* wfc   = (const float*)d_in[2];
    const float* ln1g  = (const float*)d_in[3];
    const float* ln1b  = (const float*)d_in[4];
    const float* ln2g  = (const float*)d_in[5];
    const float* ln2b  = (const float*)d_in[6];
    const int*   nrt   = (const int*)d_in[7];
    float* out = (float*)d_out;

    float* vout = (float*)d_ws;                                  // 6,422,528 B

    if (ws_size >= 9076736) {
        // new layout: wT2b | pA (wTh aliases its head; dead after conv) | pB
        float* wT2b = (float*)((char*)d_ws + 6422528);           // 1,605,632 B
        float* pA   = (float*)((char*)d_ws + 8028160);           // 524,288 B
        float* pB   = (float*)((char*)d_ws + 8552448);           // 524,288 B
        unsigned short* wTh = (unsigned short*)pA;               // 294,912 B alias

        hipLaunchKernelGGL(transpose_weights, dim3(2144), dim3(256), 0, stream,
                           wconv, wfc, wTh, wT2b);
        hipLaunchKernelGGL(conv_routing_kernel, dim3(3136), dim3(256), 0, stream,
                           x, wTh, ln1g, ln1b, nrt, vout);
        hipLaunchKernelGGL(fc_pass, dim3(512), dim3(256), 0, stream,
                           vout, wT2b, (const float*)nullptr, ln2g, ln2b, nrt, 0, pA);
        hipLaunchKernelGGL(fc_pass, dim3(512), dim3(256), 0, stream,
                           vout, wT2b, (const float*)pA, ln2g, ln2b, nrt, 1, pB);
        hipLaunchKernelGGL(fc_pass, dim3(512), dim3(256), 0, stream,
                           vout, wT2b, (const float*)pB, ln2g, ln2b, nrt, 2, pA);
        hipLaunchKernelGGL(fc_final, dim3(64), dim3(256), 0, stream,
                           pA, pB, ln2g, ln2b, nrt, out);
    } else {
        // fallback: R14's proven tight layout, 6-launch fc
        unsigned short* wTh = (unsigned short*)((char*)d_ws + 6422528);
        float* wT2b    = (float*)((char*)d_ws + 6422528);        // aliases wTh
        float* ubuf    = (float*)((char*)d_ws + 8028160);        // 65,536 B
        float* partial = (float*)((char*)d_ws + 8093696);        // 524,288 B

        hipLaunchKernelGGL(transpose_wconv, dim3(576), dim3(256), 0, stream,
                           wconv, wTh);
        hipLaunchKernelGGL(conv_routing_kernel, dim3(3136), dim3(256), 0, stream,
                           x, wTh, ln1g, ln1b, nrt, vout);
        hipLaunchKernelGGL(transpose_wfc, dim3(1568), dim3(256), 0, stream,
                           wfc, wT2b);
        for (int pass = 0; pass < 3; ++pass) {
            hipLaunchKernelGGL(fc_partial, dim3(512), dim3(256), 0, stream,
                               vout, wT2b, ubuf, nrt, pass, partial);
            hipLaunchKernelGGL(fc_combine, dim3(64), dim3(256), 0, stream,
                               partial, ln2g, ln2b, nrt, pass, ubuf, out);
        }
    }
}

// Round 7
// 291.281 us; speedup vs baseline: 3.8190x; 1.0050x over previous
//
#include <hip/hip_runtime.h>
#include <hip/hip_bf16.h>

// CapsModel: B=64 N=32 H=W=16 A=16 K=3 stride=2 -> Ho=Wo=7, M=32, SD=4, D=16
// R23: R22 structure, ONE change: conv launch_bounds (256,4) -> (256,5).
//   Evidence: R22 confirmed latency-bound model (DPP softmax -16us); conv
//   still 26% issue-idle at 4 blocks/CU (occ 46%). 5 blocks/CU = +25% issue
//   supply -> should fill to ~90% busy. (256,6) avoided: R14-era pathology
//   (compiler pins VGPR=40 + spills at cap 85; we need 48). Cap at 5 = 102,
//   safe even under a 50/50 unified-file split.
//   Tells: VGPR stays 48, WRITE_SIZE stays 6.27MB. VGPR->40 or WRITE up
//   = pathology -> revert. Flat conv = occupancy not the binder -> next
//   try 3-way j-interleave (fits under cap 102).
// R22: DPP softmax reductions (conv: row16_sum + 1 ds_swizzle xor16;
//   fc: pure DPP). R21: v_dot2_f32_f16 asm. Proven: conv 197us.
// conv structure: one site per block, 3136 x 256 thr, t-PAIRS.
//   MFMA rewrites R18/R19 lost -- no revisit w/o disasm.
// fc routing R16: 4 launches, prev-partial double-buffered. Unchanged.

#define LN_EPS 1e-5f

typedef _Float16 h2 __attribute__((ext_vector_type(2)));

__device__ __forceinline__ unsigned packh2(float a, float b) {
    const unsigned short ua = __builtin_bit_cast(unsigned short, (_Float16)a);
    const unsigned short ub = __builtin_bit_cast(unsigned short, (_Float16)b);
    return (unsigned)ua | ((unsigned)ub << 16);
}

// force v_dot2_f32_f16 (f32 += a.lo*b.lo + a.hi*b.hi, f16 inputs). (R21)
__device__ __forceinline__ float fdot2u(unsigned a, unsigned b, float c) {
    float d;
    asm("v_dot2_f32_f16 %0, %1, %2, %3" : "=v"(d) : "v"(a), "v"(b), "v"(c));
    return d;
}

// R22: DPP cross-lane add helpers (no LDS). ctrl: 0xB1=quad_perm[1,0,3,2]
// (xor1), 0x4E=quad_perm[2,3,0,1] (xor2), 0x124=row_ror:4, 0x128=row_ror:8.
template <int CTRL>
__device__ __forceinline__ float dpp_add(float x) {
    return x + __builtin_bit_cast(float,
        __builtin_amdgcn_mov_dpp(__builtin_bit_cast(int, x), CTRL, 0xF, 0xF, false));
}
// 16-lane (DPP row) all-lanes sum.
__device__ __forceinline__ float row16_sum(float x) {
    x = dpp_add<0xB1>(x);
    x = dpp_add<0x4E>(x);
    x = dpp_add<0x124>(x);
    x = dpp_add<0x128>(x);
    return x;
}
// cross-row xor16 within each 32-lane half (BitMode swizzle 0x401F).
__device__ __forceinline__ float swz_xor16(float x) {
    return __builtin_bit_cast(float,
        __builtin_amdgcn_ds_swizzle(__builtin_bit_cast(int, x), 0x401F));
}

// ---------------- weight transposes ----------------
// wTh [288][32][16] f16: row r = n*9+kl; inner idx = d*4+x (x-pairs adjacent).
__global__ __launch_bounds__(256) void transpose_wconv(
    const float* __restrict__ wconv, unsigned short* __restrict__ wTh)
{
    const int i = blockIdx.x * 256 + threadIdx.x;
    if (i < 147456) {
        const int x = i & 3, d = (i >> 2) & 3, mm = (i >> 4) & 31, r = i >> 9;
        const int n = r / 9, kl = r % 9;
        const float v = wconv[((kl * 32 + n) * 16 + x * 4 + d) * 32 + mm];
        wTh[i] = __builtin_bit_cast(unsigned short, (_Float16)v);
    }
}
// wT2b [1568][16][16] fp32: [n][m (pad 10->16, zeros)][x*4+d]
__global__ __launch_bounds__(256) void transpose_wfc(
    const float* __restrict__ wfc, float* __restrict__ wT2b)
{
    const int j = blockIdx.x * 256 + threadIdx.x;
    if (j < 401408) {
        const int xd = j & 15, mm = (j >> 4) & 15, n = j >> 8;
        const int x = xd >> 2, dd = xd & 3;
        wT2b[j] = (mm < 10) ? wfc[((n * 4 + x) * 4 + dd) * 10 + mm] : 0.f;
    }
}
// fused (roomy ws layout)
__global__ __launch_bounds__(256) void transpose_weights(
    const float* __restrict__ wconv, const float* __restrict__ wfc,
    unsigned short* __restrict__ wTh, float* __restrict__ wT2b)
{
    const int blk = blockIdx.x;
    if (blk < 576) {
        const int i = blk * 256 + threadIdx.x;
        if (i < 147456) {
            const int x = i & 3, d = (i >> 2) & 3, mm = (i >> 4) & 31, r = i >> 9;
            const int n = r / 9, kl = r % 9;
            const float v = wconv[((kl * 32 + n) * 16 + x * 4 + d) * 32 + mm];
            wTh[i] = __builtin_bit_cast(unsigned short, (_Float16)v);
        }
    } else {
        const int j = (blk - 576) * 256 + threadIdx.x;
        if (j < 401408) {
            const int xd = j & 15, mm = (j >> 4) & 15, n = j >> 8;
            const int x = xd >> 2, dd = xd & 3;
            wT2b[j] = (mm < 10) ? wfc[((n * 4 + x) * 4 + dd) * 10 + mm] : 0.f;
        }
    }
}

// ---------------- Stage 1: conv routing ----------------
__global__ __launch_bounds__(256, 5) void conv_routing_kernel(
    const float* __restrict__ x,             // [64][32][16][16][16]
    const unsigned short* __restrict__ wTh,  // [288][32][16] f16
    const float* __restrict__ ln1g,
    const float* __restrict__ ln1b,
    const int*   __restrict__ nroute,
    float* __restrict__ vout)                // [64][32][49][16]
{
    __shared__ unsigned short s_inp[288][16];  // f16 x-pairs, 9,216 B
    __shared__ float s_v[32][17];              // 2,176 B
    __shared__ float s_red[2][32][17];         // 4,352 B  => 15,744 B total

    const int tid = threadIdx.x;
    const int m   = tid & 31;
    const int g   = (tid >> 5) & 7;  // 0..7
    const int lw  = tid >> 6;        // 0..3
    const int site = blockIdx.x;
    const int b = site / 49, hw = site % 49;
    const int h = hw / 7, w = hw % 7;

    // stage inp (coalesced float4 loads, f16 pack); row = n*9+kl
    for (int i = tid; i < 1152; i += 256) {    // 288 rows * 4 quads
        const int row = i >> 2, q = i & 3;
        const int n = row / 9, kl = row % 9;
        const int k = kl / 3, l = kl % 3;
        const float4 val = *(const float4*)(
            x + ((((b * 32 + n) * 16 + (2 * h + k)) * 16 + (2 * w + l)) * 16 + q * 4));
        uint2 p;
        p.x = packh2(val.x, val.y);
        p.y = packh2(val.z, val.w);
        *(uint2*)(&s_inp[row][q * 4]) = p;
    }
    __syncthreads();

    const int R = *nroute;
    const int nkl0 = g * 36;
    const unsigned short* const wp0 = wTh + (nkl0 * 32 + m) * 16;

    for (int pass = 0; pass < R; ++pass) {
        float vn[16];
#pragma unroll
        for (int i = 0; i < 16; ++i) vn[i] = 0.f;

        if (pass == 0) {
            const unsigned short* wp = wp0;
            for (int t = 0; t < 36; ++t, wp += 512) {
                const uint4 wa = *(const uint4*)(wp);
                const uint4 wb = *(const uint4*)(wp + 8);
                const unsigned wu[8] = { wa.x, wa.y, wa.z, wa.w, wb.x, wb.y, wb.z, wb.w };
                const uint4* rp = (const uint4*)(&s_inp[nkl0 + t][0]);
                const uint4 ua = rp[0], ub = rp[1];
                const unsigned iu[8] = { ua.x, ua.y, ua.z, ua.w, ub.x, ub.y, ub.z, ub.w };
#pragma unroll
                for (int a = 0; a < 4; ++a) {
#pragma unroll
                    for (int d = 0; d < 4; ++d) {
                        vn[a * 4 + d] = fdot2u(iu[a * 2], wu[d * 2],
                            fdot2u(iu[a * 2 + 1], wu[d * 2 + 1], vn[a * 4 + d]));
                    }
                }
            }
        } else {
            float vrr[16];
#pragma unroll
            for (int i = 0; i < 16; ++i) vrr[i] = s_v[m][i];

            const unsigned short* wp = wp0;
            for (int j = 0; j < 18; ++j, wp += 1024) {   // t-pairs
                const uint4 wa0 = *(const uint4*)(wp);
                const uint4 wb0 = *(const uint4*)(wp + 8);
                const uint4 wa1 = *(const uint4*)(wp + 512);
                const uint4 wb1 = *(const uint4*)(wp + 520);
                const unsigned wu0[8] = { wa0.x, wa0.y, wa0.z, wa0.w, wb0.x, wb0.y, wb0.z, wb0.w };
                const unsigned wu1[8] = { wa1.x, wa1.y, wa1.z, wa1.w, wb1.x, wb1.y, wb1.z, wb1.w };
                const uint4* rp0 = (const uint4*)(&s_inp[nkl0 + 2 * j][0]);
                const uint4* rp1 = (const uint4*)(&s_inp[nkl0 + 2 * j + 1][0]);
                const uint4 ua0 = rp0[0], ub0 = rp0[1];
                const uint4 ua1 = rp1[0], ub1 = rp1[1];
                const unsigned iu0[8] = { ua0.x, ua0.y, ua0.z, ua0.w, ub0.x, ub0.y, ub0.z, ub0.w };
                const unsigned iu1[8] = { ua1.x, ua1.y, ua1.z, ua1.w, ub1.x, ub1.y, ub1.z, ub1.w };

                float uh0[16], uh1[16];
#pragma unroll
                for (int a = 0; a < 4; ++a) {
#pragma unroll
                    for (int d = 0; d < 4; ++d) {
                        uh0[a * 4 + d] = fdot2u(iu0[a * 2], wu0[d * 2],
                            fdot2u(iu0[a * 2 + 1], wu0[d * 2 + 1], 0.f));
                        uh1[a * 4 + d] = fdot2u(iu1[a * 2], wu1[d * 2],
                            fdot2u(iu1[a * 2 + 1], wu1[d * 2 + 1], 0.f));
                    }
                }

                float p0 = 0.f, p1 = 0.f, q0 = 0.f, q1 = 0.f;
#pragma unroll
                for (int i = 0; i < 16; i += 2) {
                    const float c0 = vrr[i], c1 = vrr[i + 1];
                    p0 = fmaf(uh0[i], c0, p0);
                    q0 = fmaf(uh0[i + 1], c1, q0);
                    p1 = fmaf(uh1[i], c0, p1);
                    q1 = fmaf(uh1[i + 1], c1, q1);
                }
                const float e0 = __expf((p0 + q0) * 0.25f);
                const float e1 = __expf((p1 + q1) * 0.25f);

                // DPP 16-lane sum + one xor16 swizzle -> 32-lane sum (R22)
                float sm0 = row16_sum(e0);
                float sm1 = row16_sum(e1);
                sm0 += swz_xor16(sm0);
                sm1 += swz_xor16(sm1);

                const float qk0 = e0 * __builtin_amdgcn_rcpf(sm0 * (1.f + 1e-10f));
                const float qk1 = e1 * __builtin_amdgcn_rcpf(sm1 * (1.f + 1e-10f));
#pragma unroll
                for (int i = 0; i < 16; ++i) {
                    vn[i] = fmaf(qk0, uh0[i], vn[i]);
                    vn[i] = fmaf(qk1, uh1[i], vn[i]);
                }
            }
        }

#pragma unroll
        for (int i = 0; i < 16; ++i) vn[i] += __shfl_xor(vn[i], 32, 64);

        if (lw >= 2) {
#pragma unroll
            for (int i = 0; i < 16; ++i) s_red[lw - 2][m][i] = vn[i];
        }
        __syncthreads();
        if (lw < 2) {
#pragma unroll
            for (int i = 0; i < 16; ++i) vn[i] += s_red[lw][m][i];
            if (lw == 1) {
#pragma unroll
                for (int i = 0; i < 16; ++i) s_red[1][m][i] = vn[i];
            }
        }
        __syncthreads();
        if (lw == 0) {
#pragma unroll
            for (int i = 0; i < 16; ++i) vn[i] += s_red[1][m][i];
            const float scale = pass ? 1.f : (1.f / 32.f);
            float mu = 0.f;
#pragma unroll
            for (int i = 0; i < 16; ++i) { vn[i] *= scale; mu += vn[i]; }
            mu *= (1.f / 16.f);
            float var = 0.f;
#pragma unroll
            for (int i = 0; i < 16; ++i) {
                const float d0 = vn[i] - mu;
                var = fmaf(d0, d0, var);
            }
            var *= (1.f / 16.f);
            const float inv = rsqrtf(var + LN_EPS);
#pragma unroll
            for (int i = 0; i < 16; ++i)
                s_v[m][i] = (vn[i] - mu) * inv * ln1g[i] + ln1b[i];
        }
        __syncthreads();
    }

    for (int p = tid; p < 512; p += 256) {
        const int mm = p >> 4, i = p & 15;
        vout[((b * 32 + mm) * 49 + hw) * 16 + i] = s_v[mm][i];
    }
}

// ---------------- Stage 2: FC routing ----------------
// fc_pass: 512 blocks = 64 b x 8 chunks; 256 thr = 16 grp x 16 ml.
// For pass>=1, each block redundantly recomputes its b's u from the
// previous pass's partial (combine+LN in LDS) - no ubuf, no extra launch.
__global__ __launch_bounds__(256, 4) void fc_pass(
    const float* __restrict__ fcin,  // [64][1568][16]
    const float* __restrict__ wT2b,  // [1568][16][16] ([n][ml][x*4+d])
    const float* __restrict__ prev,  // [512][16][16] partial from pass-1 (or null)
    const float* __restrict__ ln2g,
    const float* __restrict__ ln2b,
    const int*   __restrict__ nroute,
    const int    pass,
    float* __restrict__ pout)        // [512][16][16]
{
    __shared__ float s_red[4][16][17];
    __shared__ float s_u[16][17];

    const int R = *nroute;
    if (pass >= R) return;
    const int blk = blockIdx.x;
    const int b = blk >> 3, c = blk & 7;
    const int tid = threadIdx.x;
    const int ml = tid & 15, grp = tid >> 4;
    const int wv = tid >> 6;

    float ur[16];
    if (pass) {
        // inline combine + LN: thread (mlf, ii)
        const int mlf = tid >> 4, ii = tid & 15;
        float s = 0.f;
#pragma unroll
        for (int c2 = 0; c2 < 8; ++c2)
            s += prev[((b * 8 + c2) * 16 + mlf) * 16 + ii];
        if (pass == 1) s *= 0.1f;   // pass-0 output carries the 1/Cls scale
        float mu = s;
#pragma unroll
        for (int off = 8; off >= 1; off >>= 1) mu += __shfl_xor(mu, off, 16);
        mu *= (1.f / 16.f);
        const float d0 = s - mu;
        float var = d0 * d0;
#pragma unroll
        for (int off = 8; off >= 1; off >>= 1) var += __shfl_xor(var, off, 16);
        var *= (1.f / 16.f);
        s_u[mlf][ii] = (s - mu) * rsqrtf(var + LN_EPS) * ln2g[ii] + ln2b[ii];
        __syncthreads();
#pragma unroll
        for (int i = 0; i < 16; ++i) ur[i] = s_u[ml][i];
    }

    const float* fb = fcin + (b * 1568 + c * 196) * 16;
    const float* wb = wT2b + (c * 196 * 16) * 16;

    float un[16];
#pragma unroll
    for (int i = 0; i < 16; ++i) un[i] = 0.f;

    for (int t = 0; t < 13; ++t) {
        const int off = t * 16 + grp;
        if (off >= 196) break;
        float iv[16], wv_[16];
        const float* ip = fb + off * 16;
        const float* wp = wb + (off * 16 + ml) * 16;
#pragma unroll
        for (int q = 0; q < 4; ++q) {
            *(float4*)(&iv[q * 4]) = *(const float4*)(ip + q * 4);
            *(float4*)(&wv_[q * 4]) = *(const float4*)(wp + q * 4);
        }
        float vote[16];
#pragma unroll
        for (int a = 0; a < 4; ++a) {
#pragma unroll
            for (int d = 0; d < 4; ++d) {
                float acc = iv[a * 4 + 0] * wv_[0 + d];
                acc = fmaf(iv[a * 4 + 1], wv_[4 + d], acc);
                acc = fmaf(iv[a * 4 + 2], wv_[8 + d], acc);
                acc = fmaf(iv[a * 4 + 3], wv_[12 + d], acc);
                vote[a * 4 + d] = acc;
            }
        }
        if (pass == 0) {
#pragma unroll
            for (int i = 0; i < 16; ++i) un[i] += vote[i];
        } else {
            float l0 = vote[0] * ur[0], l1 = vote[1] * ur[1];
            float l2 = vote[2] * ur[2], l3 = vote[3] * ur[3];
#pragma unroll
            for (int i = 4; i < 16; i += 4) {
                l0 = fmaf(vote[i + 0], ur[i + 0], l0);
                l1 = fmaf(vote[i + 1], ur[i + 1], l1);
                l2 = fmaf(vote[i + 2], ur[i + 2], l2);
                l3 = fmaf(vote[i + 3], ur[i + 3], l3);
            }
            const float lg = ((l0 + l1) + (l2 + l3)) * 0.25f;
            float e = __expf(lg);
            if (ml >= 10) e = 0.f;
            // width-16 softmax sum via pure DPP (R22)
            const float sm = row16_sum(e);
            const float qk = e * __builtin_amdgcn_rcpf(sm * (1.f + 1e-10f));
#pragma unroll
            for (int i = 0; i < 16; ++i) un[i] = fmaf(qk, vote[i], un[i]);
        }
    }

#pragma unroll
    for (int i = 0; i < 16; ++i) {
        un[i] += __shfl_xor(un[i], 16, 64);
        un[i] += __shfl_xor(un[i], 32, 64);
    }
    if ((tid & 63) < 16) {
#pragma unroll
        for (int i = 0; i < 16; ++i) s_red[wv][ml][i] = un[i];
    }
    __syncthreads();
    {
        const int mlf = tid >> 4, i = tid & 15;
        const float s = s_red[0][mlf][i] + s_red[1][mlf][i]
                      + s_red[2][mlf][i] + s_red[3][mlf][i];
        pout[(blk * 16 + mlf) * 16 + i] = s;
    }
}

// fc_final: combine the last pass's partial, LN, write out.
__global__ __launch_bounds__(256) void fc_final(
    const float* __restrict__ pA,    // partial written by even passes
    const float* __restrict__ pB,    // partial written by odd passes
    const float* __restrict__ ln2g,
    const float* __restrict__ ln2b,
    const int*   __restrict__ nroute,
    float* __restrict__ out)         // [64][10][16]
{
    const int R = *nroute;
    const float* P = ((R - 1) & 1) ? pB : pA;
    const int b = blockIdx.x;
    const int tid = threadIdx.x;
    const int i = tid & 15, ml = tid >> 4;

    float s = 0.f;
#pragma unroll
    for (int c = 0; c < 8; ++c)
        s += P[((b * 8 + c) * 16 + ml) * 16 + i];
    if (R == 1) s *= 0.1f;

    float mu = s;
#pragma unroll
    for (int off = 8; off >= 1; off >>= 1) mu += __shfl_xor(mu, off, 16);
    mu *= (1.f / 16.f);
    const float d0 = s - mu;
    float var = d0 * d0;
#pragma unroll
    for (int off = 8; off >= 1; off >>= 1) var += __shfl_xor(var, off, 16);
    var *= (1.f / 16.f);
    const float r = (s - mu) * rsqrtf(var + LN_EPS) * ln2g[i] + ln2b[i];

    if (ml < 10) out[(b * 10 + ml) * 16 + i] = r;
}

// ---------------- fallback 6-launch fc kernels (proven R14 path) ----------------
__global__ __launch_bounds__(256, 4) void fc_partial(
    const float* __restrict__ fcin, const float* __restrict__ wT2b,
    const float* __restrict__ u, const int* __restrict__ nroute,
    const int pass, float* __restrict__ partial)
{
    __shared__ float s_red[4][16][17];
    const int R = *nroute;
    if (pass >= R) return;
    const int blk = blockIdx.x;
    const int b = blk >> 3, c = blk & 7;
    const int tid = threadIdx.x;
    const int ml = tid & 15, grp = tid >> 4;
    const int wv = tid >> 6;
    const float* fb = fcin + (b * 1568 + c * 196) * 16;
    const float* wb = wT2b + (c * 196 * 16) * 16;

    float un[16];
#pragma unroll
    for (int i = 0; i < 16; ++i) un[i] = 0.f;
    float ur[16];
    if (pass) {
#pragma unroll
        for (int q = 0; q < 4; ++q)
            *(float4*)(&ur[q * 4]) = *(const float4*)(u + (b * 16 + ml) * 16 + q * 4);
    }
    for (int t = 0; t < 13; ++t) {
        const int off = t * 16 + grp;
        if (off >= 196) break;
        float iv[16], wv_[16];
        const float* ip = fb + off * 16;
        const float* wp = wb + (off * 16 + ml) * 16;
#pragma unroll
        for (int q = 0; q < 4; ++q) {
            *(float4*)(&iv[q * 4]) = *(const float4*)(ip + q * 4);
            *(float4*)(&wv_[q * 4]) = *(const float4*)(wp + q * 4);
        }
        float vote[16];
#pragma unroll
        for (int a = 0; a < 4; ++a) {
#pragma unroll
            for (int d = 0; d < 4; ++d) {
                float acc = iv[a * 4 + 0] * wv_[0 + d];
                acc = fmaf(iv[a * 4 + 1], wv_[4 + d], acc);
                acc = fmaf(iv[a * 4 + 2], wv_[8 + d], acc);
                acc = fmaf(iv[a * 4 + 3], wv_[12 + d], acc);
                vote[a * 4 + d] = acc;
            }
        }
        if (pass == 0) {
#pragma unroll
            for (int i = 0; i < 16; ++i) un[i] += vote[i];
        } else {
            float l0 = vote[0] * ur[0], l1 = vote[1] * ur[1];
            float l2 = vote[2] * ur[2], l3 = vote[3] * ur[3];
#pragma unroll
            for (int i = 4; i < 16; i += 4) {
                l0 = fmaf(vote[i + 0], ur[i + 0], l0);
                l1 = fmaf(vote[i + 1], ur[i + 1], l1);
                l2 = fmaf(vote[i + 2], ur[i + 2], l2);
                l3 = fmaf(vote[i + 3], ur[i + 3], l3);
            }
            const float lg = ((l0 + l1) + (l2 + l3)) * 0.25f;
            float e = __expf(lg);
            if (ml >= 10) e = 0.f;
            float sm = e;
#pragma unroll
            for (int off2 = 8; off2 >= 1; off2 >>= 1)
                sm += __shfl_xor(sm, off2, 16);
            const float qk = e * __builtin_amdgcn_rcpf(sm * (1.f + 1e-10f));
#pragma unroll
            for (int i = 0; i < 16; ++i) un[i] = fmaf(qk, vote[i], un[i]);
        }
    }
#pragma unroll
    for (int i = 0; i < 16; ++i) {
        un[i] += __shfl_xor(un[i], 16, 64);
        un[i] += __shfl_xor(un[i], 32, 64);
    }
    if ((tid & 63) < 16) {
#pragma unroll
        for (int i = 0; i < 16; ++i) s_red[wv][ml][i] = un[i];
    }
    __syncthreads();
    {
        const int mlf = tid >> 4, i = tid & 15;
        const float s = s_red[0][mlf][i] + s_red[1][mlf][i]
                      + s_red[2][mlf][i] + s_red[3][mlf][i];
        partial[(blk * 16 + mlf) * 16 + i] = s;
    }
}

__global__ __launch_bounds__(256) void fc_combine(
    const float* __restrict__ partial, const float* __restrict__ ln2g,
    const float* __restrict__ ln2b, const int* __restrict__ nroute,
    const int pass, float* __restrict__ u, float* __restrict__ out)
{
    const int R = *nroute;
    if (pass >= R) return;
    const int b = blockIdx.x;
    const int tid = threadIdx.x;
    const int i = tid & 15, ml = tid >> 4;
    float s = 0.f;
#pragma unroll
    for (int c = 0; c < 8; ++c)
        s += partial[((b * 8 + c) * 16 + ml) * 16 + i];
    if (pass == 0) s *= 0.1f;
    float mu = s;
#pragma unroll
    for (int off = 8; off >= 1; off >>= 1) mu += __shfl_xor(mu, off, 16);
    mu *= (1.f / 16.f);
    const float d0 = s - mu;
    float var = d0 * d0;
#pragma unroll
    for (int off = 8; off >= 1; off >>= 1) var += __shfl_xor(var, off, 16);
    var *= (1.f / 16.f);
    const float r = (s - mu) * rsqrtf(var + LN_EPS) * ln2g[i] + ln2b[i];
    u[(b * 16 + ml) * 16 + i] = r;
    if (pass == R - 1 && ml < 10) out[(b * 10 + ml) * 16 + i] = r;
}

extern "C" void kernel_launch(void* const* d_in, const int* in_sizes, int n_in,
                              void* d_out, int out_size, void* d_ws, size_t ws_size,
                              hipStream_t stream) {
    const float* x     = (const float*)d_in[0];
    const float* wconv = (const float*)d_in[1];
    const float* wfc   = (const float*)d_in[2];
    const float* ln1g  = (const float*)d_in[3];
    const float* ln1b  = (const float*)d_in[4];
    const float* ln2g  = (const float*)d_in[5];
    const float* ln2b  = (const float*)d_in[6];
    const int*   nrt   = (const int*)d_in[7];
    float* out = (float*)d_out;

    float* vout = (float*)d_ws;                                  // 6,422,528 B

    if (ws_size >= 9076736) {
        // new layout: wT2b | pA (wTh aliases its head; dead after conv) | pB
        float* wT2b = (float*)((char*)d_ws + 6422528);           // 1,605,632 B
        float* pA   = (float*)((char*)d_ws + 8028160);           // 524,288 B
        float* pB   = (float*)((char*)d_ws + 8552448);           // 524,288 B
        unsigned short* wTh = (unsigned short*)pA;               // 294,912 B alias

        hipLaunchKernelGGL(transpose_weights, dim3(2144), dim3(256), 0, stream,
                           wconv, wfc, wTh, wT2b);
        hipLaunchKernelGGL(conv_routing_kernel, dim3(3136), dim3(256), 0, stream,
                           x, wTh, ln1g, ln1b, nrt, vout);
        hipLaunchKernelGGL(fc_pass, dim3(512), dim3(256), 0, stream,
                           vout, wT2b, (const float*)nullptr, ln2g, ln2b, nrt, 0, pA);
        hipLaunchKernelGGL(fc_pass, dim3(512), dim3(256), 0, stream,
                           vout, wT2b, (const float*)pA, ln2g, ln2b, nrt, 1, pB);
        hipLaunchKernelGGL(fc_pass, dim3(512), dim3(256), 0, stream,
                           vout, wT2b, (const float*)pB, ln2g, ln2b, nrt, 2, pA);
        hipLaunchKernelGGL(fc_final, dim3(64), dim3(256), 0, stream,
                           pA, pB, ln2g, ln2b, nrt, out);
    } else {
        // fallback: R14's proven tight layout, 6-launch fc
        unsigned short* wTh = (unsigned short*)((char*)d_ws + 6422528);
        float* wT2b    = (float*)((char*)d_ws + 6422528);        // aliases wTh
        float* ubuf    = (float*)((char*)d_ws + 8028160);        // 65,536 B
        float* partial = (float*)((char*)d_ws + 8093696);        // 524,288 B

        hipLaunchKernelGGL(transpose_wconv, dim3(576), dim3(256), 0, stream,
                           wconv, wTh);
        hipLaunchKernelGGL(conv_routing_kernel, dim3(3136), dim3(256), 0, stream,
                           x, wTh, ln1g, ln1b, nrt, vout);
        hipLaunchKernelGGL(transpose_wfc, dim3(1568), dim3(256), 0, stream,
                           wfc, wT2b);
        for (int pass = 0; pass < 3; ++pass) {
            hipLaunchKernelGGL(fc_partial, dim3(512), dim3(256), 0, stream,
                               vout, wT2b, ubuf, nrt, pass, partial);
            hipLaunchKernelGGL(fc_combine, dim3(64), dim3(256), 0, stream,
                               partial, ln2g, ln2b, nrt, pass, ubuf, out);
        }
    }
}